// Round 1
// baseline (6267.060 us; speedup 1.0000x reference)
//
#include <hip/hip_runtime.h>
#include <math.h>

// GCN: h1 = relu(norm_dst * A * (norm_src * x) @ W1 + b1)
//      h2 = relu(norm_dst * A * (norm_src * h1) @ W2 + b2)
//      hg = mean_per_graph(h2); out = relu(hg@Wr1+br1)@Wr2+br2
// d_out = [out (64*128) | h2 (N*128)]

#define D 128

// ---------------- degree + norm ----------------
__global__ __launch_bounds__(256) void k_degree(const int* __restrict__ src,
                                                const int* __restrict__ dst,
                                                float* __restrict__ deg_out,
                                                float* __restrict__ deg_in, int E) {
  int e = blockIdx.x * 256 + threadIdx.x;
  if (e < E) {
    atomicAdd(&deg_out[src[e]], 1.0f);
    atomicAdd(&deg_in[dst[e]], 1.0f);
  }
}

__global__ __launch_bounds__(256) void k_norm(float* __restrict__ deg, int n) {
  int i = blockIdx.x * 256 + threadIdx.x;
  if (i < n) {
    float d = deg[i];
    deg[i] = 1.0f / sqrtf(fmaxf(d, 1.0f));
  }
}

// ---------------- GEMM: C[N x 128] = (scale[:,None] * A) @ W ----------------
// block = 256 threads, tile = 32 rows x 128 cols, thread = 4x4. Requires N%32==0.
__global__ __launch_bounds__(256) void k_gemm(const float* __restrict__ A,
                                              const float* __restrict__ W,
                                              const float* __restrict__ scale,
                                              float* __restrict__ C) {
  __shared__ float xs[32][D];
  const int r0 = blockIdx.x * 32;
  const int t = threadIdx.x;
  const float4* A4 = (const float4*)A;
  for (int idx = t; idx < 32 * 32; idx += 256) {
    int r = idx >> 5, c4 = idx & 31;
    float4 v = A4[(size_t)(r0 + r) * 32 + c4];
    float s = scale[r0 + r];
    v.x *= s; v.y *= s; v.z *= s; v.w *= s;
    *(float4*)&xs[r][c4 * 4] = v;
  }
  __syncthreads();
  const int jg = t & 31;  // col group: cols jg*4..jg*4+3
  const int rg = t >> 5;  // row group: rows rg*4..rg*4+3
  const float4* W4 = (const float4*)W;
  float acc[4][4];
#pragma unroll
  for (int r = 0; r < 4; ++r)
#pragma unroll
    for (int c = 0; c < 4; ++c) acc[r][c] = 0.0f;

  for (int k = 0; k < D; k += 4) {
    float4 a[4], w[4];
#pragma unroll
    for (int r = 0; r < 4; ++r) a[r] = *(const float4*)&xs[rg * 4 + r][k];
#pragma unroll
    for (int u = 0; u < 4; ++u) w[u] = W4[(size_t)(k + u) * 32 + jg];
#pragma unroll
    for (int r = 0; r < 4; ++r) {
      const float* ar = (const float*)&a[r];
#pragma unroll
      for (int u = 0; u < 4; ++u) {
        const float* wu = (const float*)&w[u];
#pragma unroll
        for (int c = 0; c < 4; ++c) acc[r][c] += ar[u] * wu[c];
      }
    }
  }
#pragma unroll
  for (int r = 0; r < 4; ++r) {
    float4 o;
    o.x = acc[r][0]; o.y = acc[r][1]; o.z = acc[r][2]; o.w = acc[r][3];
    *(float4*)&C[(size_t)(r0 + rg * 4 + r) * D + jg * 4] = o;
  }
}

// ---------------- SpMM scatter: out[dst] += P[src] ----------------
// thread = (edge, float4-chunk q in [0,32))
__global__ __launch_bounds__(256) void k_spmm(const float4* __restrict__ P,
                                              const int* __restrict__ src,
                                              const int* __restrict__ dst,
                                              float* __restrict__ out, int E) {
  int tid = blockIdx.x * 256 + threadIdx.x;
  int e = tid >> 5;
  if (e >= E) return;
  int q = tid & 31;
  int s = src[e], d = dst[e];
  float4 v = P[(size_t)s * 32 + q];
  float* o = out + (size_t)d * D + q * 4;
  atomicAdd(o + 0, v.x);
  atomicAdd(o + 1, v.y);
  atomicAdd(o + 2, v.z);
  atomicAdd(o + 3, v.w);
}

// ---------------- H = relu(H * norm_dst + b) in place ----------------
__global__ __launch_bounds__(256) void k_post(float4* __restrict__ H,
                                              const float* __restrict__ norm_dst,
                                              const float* __restrict__ bias,
                                              int N) {
  int tid = blockIdx.x * 256 + threadIdx.x;
  if (tid >= N * 32) return;
  int row = tid >> 5, q = tid & 31;
  float nd = norm_dst[row];
  float4 b = ((const float4*)bias)[q];
  float4 v = H[tid];
  v.x = fmaxf(v.x * nd + b.x, 0.0f);
  v.y = fmaxf(v.y * nd + b.y, 0.0f);
  v.z = fmaxf(v.z * nd + b.z, 0.0f);
  v.w = fmaxf(v.w * nd + b.w, 0.0f);
  H[tid] = v;
}

// ---------------- same, plus pool accumulation ----------------
__global__ __launch_bounds__(256) void k_post_pool(float4* __restrict__ H,
                                                   const float* __restrict__ norm_dst,
                                                   const float* __restrict__ bias,
                                                   const int* __restrict__ gid,
                                                   float* __restrict__ pool, int N) {
  int tid = blockIdx.x * 256 + threadIdx.x;
  if (tid >= N * 32) return;
  int row = tid >> 5, q = tid & 31;
  float nd = norm_dst[row];
  float4 b = ((const float4*)bias)[q];
  float4 v = H[tid];
  v.x = fmaxf(v.x * nd + b.x, 0.0f);
  v.y = fmaxf(v.y * nd + b.y, 0.0f);
  v.z = fmaxf(v.z * nd + b.z, 0.0f);
  v.w = fmaxf(v.w * nd + b.w, 0.0f);
  H[tid] = v;
  int g = gid[row];
  float* p = pool + (size_t)g * D + q * 4;
  atomicAdd(p + 0, v.x);
  atomicAdd(p + 1, v.y);
  atomicAdd(p + 2, v.z);
  atomicAdd(p + 3, v.w);
}

// ---------------- per-graph node counts (LDS histogram) ----------------
__global__ __launch_bounds__(256) void k_counts(const int* __restrict__ gid,
                                                float* __restrict__ counts, int N) {
  __shared__ int h[64];
  if (threadIdx.x < 64) h[threadIdx.x] = 0;
  __syncthreads();
  int i = blockIdx.x * 256 + threadIdx.x;
  if (i < N) atomicAdd(&h[gid[i]], 1);
  __syncthreads();
  if (threadIdx.x < 64 && h[threadIdx.x] > 0)
    atomicAdd(&counts[threadIdx.x], (float)h[threadIdx.x]);
}

// ---------------- readout MLP: out = relu(hg@Wr1+br1)@Wr2+br2 ----------------
__global__ __launch_bounds__(128) void k_readout(const float* __restrict__ pool,
                                                 const float* __restrict__ counts,
                                                 const float* __restrict__ Wr1,
                                                 const float* __restrict__ br1,
                                                 const float* __restrict__ Wr2,
                                                 const float* __restrict__ br2,
                                                 float* __restrict__ out) {
  int g = blockIdx.x;
  int j = threadIdx.x;
  __shared__ float hg[D];
  __shared__ float t1[D];
  float cnt = fmaxf(counts[g], 1.0f);
  hg[j] = pool[(size_t)g * D + j] / cnt;
  __syncthreads();
  float a = br1[j];
  for (int k = 0; k < D; ++k) a += hg[k] * Wr1[(size_t)k * D + j];
  t1[j] = fmaxf(a, 0.0f);
  __syncthreads();
  float b = br2[j];
  for (int k = 0; k < D; ++k) b += t1[k] * Wr2[(size_t)k * D + j];
  out[(size_t)g * D + j] = b;
}

extern "C" void kernel_launch(void* const* d_in, const int* in_sizes, int n_in,
                              void* d_out, int out_size, void* d_ws, size_t ws_size,
                              hipStream_t stream) {
  const float* x   = (const float*)d_in[0];
  const int* edge  = (const int*)d_in[1];
  const int* gid   = (const int*)d_in[2];
  // d_in[3] = num_graphs (=64, hardcoded below; grid dims must be static anyway)
  const float* W1  = (const float*)d_in[4];
  const float* b1  = (const float*)d_in[5];
  const float* W2  = (const float*)d_in[6];
  const float* b2  = (const float*)d_in[7];
  const float* Wr1 = (const float*)d_in[8];
  const float* br1 = (const float*)d_in[9];
  const float* Wr2 = (const float*)d_in[10];
  const float* br2 = (const float*)d_in[11];

  const int N = in_sizes[0] / D;   // 100000
  const int E = in_sizes[1] / 2;   // 1600000
  const int* src = edge;
  const int* dst = edge + E;

  float* ws = (float*)d_ws;
  float* bufA    = ws;                              // N*128: projection buffer
  float* bufB    = bufA + (size_t)N * D;            // N*128: agg1 / h1
  float* deg_out = bufB + (size_t)N * D;            // N  (becomes norm_src)
  float* deg_in  = deg_out + N;                     // N  (becomes norm_dst)
  float* pool    = deg_in + N;                      // 64*128
  float* counts  = pool + 64 * D;                   // 64
  size_t need_bytes = ((size_t)2 * N * D + 2 * N + 64 * D + 64) * sizeof(float);
  if (ws_size < need_bytes) return;  // insufficient workspace -> visible failure

  float* out_g = (float*)d_out;          // 64*128
  float* h_out = out_g + 64 * D;         // N*128 (layer-2 agg scatters here)

  // zero accumulation targets (bufB..counts are contiguous)
  hipMemsetAsync(bufB, 0, ((size_t)N * D + 2 * N + 64 * D + 64) * sizeof(float), stream);
  hipMemsetAsync(d_out, 0, ((size_t)64 * D + (size_t)N * D) * sizeof(float), stream);

  k_degree<<<(E + 255) / 256, 256, 0, stream>>>(src, dst, deg_out, deg_in, E);
  k_norm<<<(2 * N + 255) / 256, 256, 0, stream>>>(deg_out, 2 * N);  // deg arrays adjacent

  // layer 1
  k_gemm<<<N / 32, 256, 0, stream>>>(x, W1, deg_out, bufA);
  k_spmm<<<(E * 32 + 255) / 256, 256, 0, stream>>>((const float4*)bufA, src, dst, bufB, E);
  k_post<<<(N * 32 + 255) / 256, 256, 0, stream>>>((float4*)bufB, deg_in, b1, N);

  // layer 2 (aggregate straight into d_out's h region)
  k_gemm<<<N / 32, 256, 0, stream>>>(bufB, W2, deg_out, bufA);
  k_spmm<<<(E * 32 + 255) / 256, 256, 0, stream>>>((const float4*)bufA, src, dst, h_out, E);
  k_post_pool<<<(N * 32 + 255) / 256, 256, 0, stream>>>((float4*)h_out, deg_in, b2, gid, pool, N);

  // pooling finalize + readout
  k_counts<<<(N + 255) / 256, 256, 0, stream>>>(gid, counts, N);
  k_readout<<<64, 128, 0, stream>>>(pool, counts, Wr1, br1, Wr2, br2, out_g);
}

// Round 2
// 905.561 us; speedup vs baseline: 6.9206x; 6.9206x over previous
//
#include <hip/hip_runtime.h>
#include <math.h>

// GCN: h1 = relu(norm_dst * A * (norm_src * x) @ W1 + b1)
//      h2 = relu(norm_dst * A * (norm_src * h1) @ W2 + b2)
//      hg = mean_per_graph(h2); out = relu(hg@Wr1+br1)@Wr2+br2
// d_out = [out (64*128) | h2 (N*128)]
//
// R2: scatter-atomic SpMM (2685us, 3.2GB atomic write-through) replaced by
// CSR-by-dst build + register-accumulating gather (one wave per node),
// with norm_dst+bias+relu fused into the gather epilogue. Pooling via
// sorted-graph_id segment reduction instead of 12.8M atomics.

#define D 128

// ---------------- degrees (int atomics) ----------------
__global__ __launch_bounds__(256) void k_degree(const int* __restrict__ src,
                                                const int* __restrict__ dst,
                                                int* __restrict__ deg_out,
                                                int* __restrict__ deg_in, int E) {
  int e = blockIdx.x * 256 + threadIdx.x;
  if (e < E) {
    atomicAdd(&deg_out[src[e]], 1);
    atomicAdd(&deg_in[dst[e]], 1);
  }
}

// norm_src = rsqrt(max(deg,1)), in place over the int buffer
__global__ __launch_bounds__(256) void k_norm(int* __restrict__ deg_i, int n) {
  int i = blockIdx.x * 256 + threadIdx.x;
  if (i < n) {
    float d = (float)deg_i[i];
    ((float*)deg_i)[i] = rsqrtf(fmaxf(d, 1.0f));
  }
}

// ---------------- exclusive scan of deg_in -> row_ptr (single block) --------
__global__ __launch_bounds__(1024) void k_scan(const int* __restrict__ deg,
                                               int* __restrict__ row_ptr, int N) {
  __shared__ int partial[1024];
  const int t = threadIdx.x;
  const int chunk = (N + 1023) / 1024;
  const int begin = t * chunk;
  const int end = min(begin + chunk, N);
  int s = 0;
  for (int i = begin; i < end; ++i) s += deg[i];
  partial[t] = s;
  __syncthreads();
  for (int off = 1; off < 1024; off <<= 1) {
    int add = (t >= off) ? partial[t - off] : 0;
    __syncthreads();
    partial[t] += add;
    __syncthreads();
  }
  int run = partial[t] - s;  // exclusive base for this chunk
  for (int i = begin; i < end; ++i) {
    row_ptr[i] = run;
    run += deg[i];
  }
}

// ---------------- bucket edges into CSR (mutates row_ptr to inclusive-end) --
__global__ __launch_bounds__(256) void k_bucket(const int* __restrict__ src,
                                                const int* __restrict__ dst,
                                                int* __restrict__ row_ptr,
                                                int* __restrict__ csr, int E) {
  int e = blockIdx.x * 256 + threadIdx.x;
  if (e < E) {
    int d = dst[e];
    int pos = atomicAdd(&row_ptr[d], 1);
    csr[pos] = src[e];
  }
}

// ---------------- GEMM: C[N x 128] = (scale[:,None] * A) @ W ----------------
// block = 256 threads, tile = 32 rows x 128 cols, thread = 4x4. Requires N%32==0.
__global__ __launch_bounds__(256) void k_gemm(const float* __restrict__ A,
                                              const float* __restrict__ W,
                                              const float* __restrict__ scale,
                                              float* __restrict__ C) {
  __shared__ float xs[32][D];
  const int r0 = blockIdx.x * 32;
  const int t = threadIdx.x;
  const float4* A4 = (const float4*)A;
  for (int idx = t; idx < 32 * 32; idx += 256) {
    int r = idx >> 5, c4 = idx & 31;
    float4 v = A4[(size_t)(r0 + r) * 32 + c4];
    float s = scale[r0 + r];
    v.x *= s; v.y *= s; v.z *= s; v.w *= s;
    *(float4*)&xs[r][c4 * 4] = v;
  }
  __syncthreads();
  const int jg = t & 31;
  const int rg = t >> 5;
  const float4* W4 = (const float4*)W;
  float acc[4][4];
#pragma unroll
  for (int r = 0; r < 4; ++r)
#pragma unroll
    for (int c = 0; c < 4; ++c) acc[r][c] = 0.0f;

  for (int k = 0; k < D; k += 4) {
    float4 a[4], w[4];
#pragma unroll
    for (int r = 0; r < 4; ++r) a[r] = *(const float4*)&xs[rg * 4 + r][k];
#pragma unroll
    for (int u = 0; u < 4; ++u) w[u] = W4[(size_t)(k + u) * 32 + jg];
#pragma unroll
    for (int r = 0; r < 4; ++r) {
      const float* ar = (const float*)&a[r];
#pragma unroll
      for (int u = 0; u < 4; ++u) {
        const float* wu = (const float*)&w[u];
#pragma unroll
        for (int c = 0; c < 4; ++c) acc[r][c] += ar[u] * wu[c];
      }
    }
  }
#pragma unroll
  for (int r = 0; r < 4; ++r) {
    float4 o;
    o.x = acc[r][0]; o.y = acc[r][1]; o.z = acc[r][2]; o.w = acc[r][3];
    *(float4*)&C[(size_t)(r0 + rg * 4 + r) * D + jg * 4] = o;
  }
}

// ---------------- gather SpMM + fused norm_dst/bias/relu ----------------
// one wave (64 lanes) per dst node; lane owns a float2 column slice.
// row_ptr has been mutated by k_bucket: row_ptr[n] == end of node n's bucket,
// start = (n==0) ? 0 : row_ptr[n-1].
__global__ __launch_bounds__(256) void k_gather(const float2* __restrict__ P,
                                                const int* __restrict__ row_ptr,
                                                const int* __restrict__ csr,
                                                const float* __restrict__ bias,
                                                float2* __restrict__ outH, int N) {
  int wid = (blockIdx.x * 256 + threadIdx.x) >> 6;
  if (wid >= N) return;
  int lane = threadIdx.x & 63;
  int end = row_ptr[wid];
  int start = (wid == 0) ? 0 : row_ptr[wid - 1];
  float2 acc = {0.0f, 0.0f};
  for (int base = start; base < end; base += 64) {
    int nb = min(64, end - base);
    int idx = (base + lane < end) ? csr[base + lane] : 0;
    int j = 0;
    for (; j + 4 <= nb; j += 4) {
      int s0 = __shfl(idx, j), s1 = __shfl(idx, j + 1);
      int s2 = __shfl(idx, j + 2), s3 = __shfl(idx, j + 3);
      float2 v0 = P[(size_t)s0 * 64 + lane];
      float2 v1 = P[(size_t)s1 * 64 + lane];
      float2 v2 = P[(size_t)s2 * 64 + lane];
      float2 v3 = P[(size_t)s3 * 64 + lane];
      acc.x += v0.x + v1.x + v2.x + v3.x;
      acc.y += v0.y + v1.y + v2.y + v3.y;
    }
    for (; j < nb; ++j) {
      int s = __shfl(idx, j);
      float2 v = P[(size_t)s * 64 + lane];
      acc.x += v.x;
      acc.y += v.y;
    }
  }
  float nd = rsqrtf(fmaxf((float)(end - start), 1.0f));
  float2 b = ((const float2*)bias)[lane];
  float2 o;
  o.x = fmaxf(acc.x * nd + b.x, 0.0f);
  o.y = fmaxf(acc.y * nd + b.y, 0.0f);
  outH[(size_t)wid * 64 + lane] = o;
}

// ---------------- per-graph node counts (LDS histogram, int) ----------------
__global__ __launch_bounds__(256) void k_counts(const int* __restrict__ gid,
                                                int* __restrict__ counts, int N) {
  __shared__ int h[64];
  if (threadIdx.x < 64) h[threadIdx.x] = 0;
  __syncthreads();
  int i = blockIdx.x * 256 + threadIdx.x;
  if (i < N) atomicAdd(&h[gid[i]], 1);
  __syncthreads();
  if (threadIdx.x < 64 && h[threadIdx.x] > 0)
    atomicAdd(&counts[threadIdx.x], h[threadIdx.x]);
}

// ---------------- graph_ptr = exclusive scan of counts (65 entries) ---------
__global__ __launch_bounds__(64) void k_gptr(const int* __restrict__ counts,
                                             int* __restrict__ gptr) {
  if (threadIdx.x == 0) {
    int run = 0;
    for (int g = 0; g < 64; ++g) {
      gptr[g] = run;
      run += counts[g];
    }
    gptr[64] = run;
  }
}

// ---------------- segment-sum pooling over sorted graph_id ----------------
// grid = 64 graphs x 8 chunks; block 256 = 128 cols x 2 row-partials.
__global__ __launch_bounds__(256) void k_pool(const float* __restrict__ H,
                                              const int* __restrict__ gptr,
                                              float* __restrict__ pool) {
  int g = blockIdx.x >> 3, chunk = blockIdx.x & 7;
  int col = threadIdx.x & 127, rpar = threadIdx.x >> 7;
  int s = gptr[g], e = gptr[g + 1];
  float acc = 0.0f;
  for (int r = s + chunk * 2 + rpar; r < e; r += 16)
    acc += H[(size_t)r * D + col];
  __shared__ float red[256];
  red[threadIdx.x] = acc;
  __syncthreads();
  if (rpar == 0) atomicAdd(&pool[g * D + col], acc + red[threadIdx.x + 128]);
}

// ---------------- readout MLP: out = relu(hg@Wr1+br1)@Wr2+br2 ----------------
__global__ __launch_bounds__(128) void k_readout(const float* __restrict__ pool,
                                                 const int* __restrict__ counts,
                                                 const float* __restrict__ Wr1,
                                                 const float* __restrict__ br1,
                                                 const float* __restrict__ Wr2,
                                                 const float* __restrict__ br2,
                                                 float* __restrict__ out) {
  int g = blockIdx.x;
  int j = threadIdx.x;
  __shared__ float hg[D];
  __shared__ float t1[D];
  float cnt = fmaxf((float)counts[g], 1.0f);
  hg[j] = pool[(size_t)g * D + j] / cnt;
  __syncthreads();
  float a = br1[j];
  for (int k = 0; k < D; ++k) a += hg[k] * Wr1[(size_t)k * D + j];
  t1[j] = fmaxf(a, 0.0f);
  __syncthreads();
  float b = br2[j];
  for (int k = 0; k < D; ++k) b += t1[k] * Wr2[(size_t)k * D + j];
  out[(size_t)g * D + j] = b;
}

extern "C" void kernel_launch(void* const* d_in, const int* in_sizes, int n_in,
                              void* d_out, int out_size, void* d_ws, size_t ws_size,
                              hipStream_t stream) {
  const float* x   = (const float*)d_in[0];
  const int* edge  = (const int*)d_in[1];
  const int* gid   = (const int*)d_in[2];
  const float* W1  = (const float*)d_in[4];
  const float* b1  = (const float*)d_in[5];
  const float* W2  = (const float*)d_in[6];
  const float* b2  = (const float*)d_in[7];
  const float* Wr1 = (const float*)d_in[8];
  const float* br1 = (const float*)d_in[9];
  const float* Wr2 = (const float*)d_in[10];
  const float* br2 = (const float*)d_in[11];

  const int N = in_sizes[0] / D;   // 100000
  const int E = in_sizes[1] / 2;   // 1600000
  const int* src = edge;
  const int* dst = edge + E;

  // workspace layout
  float* bufA   = (float*)d_ws;                   // N*128 (projection)
  float* bufB   = bufA + (size_t)N * D;           // N*128 (h1); first N ints = deg_in
  int* deg_in   = (int*)bufB;                     //   (consumed before gather1 writes)
  int* row_ptr  = (int*)(bufB + (size_t)N * D);   // N ints (mutated by bucket)
  int* csr      = row_ptr + N;                    // E ints
  int* deg_out  = csr + E;                        // N ints -> norm_src floats in place
  float* pool   = (float*)(deg_out + N);          // 64*128
  int* counts   = (int*)(pool + 64 * D);          // 64
  int* gptr     = counts + 64;                    // 65
  size_t need = ((size_t)2 * N * D + 2 * N + E + 64 * D + 64 + 65) * sizeof(float);
  if (ws_size < need) return;

  float* out_g = (float*)d_out;      // 64*128
  float* h_out = out_g + 64 * D;     // N*128

  hipMemsetAsync(deg_out, 0, (size_t)N * sizeof(int), stream);
  hipMemsetAsync(deg_in, 0, (size_t)N * sizeof(int), stream);
  hipMemsetAsync(pool, 0, (64 * D + 64) * sizeof(float), stream);  // pool+counts

  // graph structure
  k_degree<<<(E + 255) / 256, 256, 0, stream>>>(src, dst, deg_out, deg_in, E);
  k_scan<<<1, 1024, 0, stream>>>(deg_in, row_ptr, N);
  k_bucket<<<(E + 255) / 256, 256, 0, stream>>>(src, dst, row_ptr, csr, E);
  k_norm<<<(N + 255) / 256, 256, 0, stream>>>(deg_out, N);
  const float* norm_src = (const float*)deg_out;

  // layer 1
  k_gemm<<<N / 32, 256, 0, stream>>>(x, W1, norm_src, bufA);
  k_gather<<<(N * 64 + 255) / 256, 256, 0, stream>>>(
      (const float2*)bufA, row_ptr, csr, b1, (float2*)bufB, N);

  // layer 2 (gather writes straight into d_out's h region)
  k_gemm<<<N / 32, 256, 0, stream>>>(bufB, W2, norm_src, bufA);
  k_gather<<<(N * 64 + 255) / 256, 256, 0, stream>>>(
      (const float2*)bufA, row_ptr, csr, b2, (float2*)h_out, N);

  // pooling + readout
  k_counts<<<(N + 255) / 256, 256, 0, stream>>>(gid, counts, N);
  k_gptr<<<1, 64, 0, stream>>>(counts, gptr);
  k_pool<<<64 * 8, 256, 0, stream>>>(h_out, gptr, pool);
  k_readout<<<64, 128, 0, stream>>>(pool, counts, Wr1, br1, Wr2, br2, out_g);
}

// Round 3
// 756.281 us; speedup vs baseline: 8.2867x; 1.1974x over previous
//
#include <hip/hip_runtime.h>
#include <math.h>

// GCN: h1 = relu(norm_dst * A * (norm_src * x) @ W1 + b1)
//      h2 = relu(norm_dst * A * (norm_src * h1) @ W2 + b2)
//      hg = mean_per_graph(h2); out = relu(hg@Wr1+br1)@Wr2+br2
// d_out = [out (64*128) | h2 (N*128)]
//
// R2: scatter-atomic SpMM -> CSR-by-dst + register gather (fused norm/bias/relu).
// R3: single-block scan (164us, 0.15% occupancy, uncoalesced) -> 3-phase
//     hierarchical scan (int4 coalesced, ~15us total).

#define D 128

// ---------------- degrees (int atomics) ----------------
__global__ __launch_bounds__(256) void k_degree(const int* __restrict__ src,
                                                const int* __restrict__ dst,
                                                int* __restrict__ deg_out,
                                                int* __restrict__ deg_in, int E) {
  int e = blockIdx.x * 256 + threadIdx.x;
  if (e < E) {
    atomicAdd(&deg_out[src[e]], 1);
    atomicAdd(&deg_in[dst[e]], 1);
  }
}

// norm_src = rsqrt(max(deg,1)), in place over the int buffer
__global__ __launch_bounds__(256) void k_norm(int* __restrict__ deg_i, int n) {
  int i = blockIdx.x * 256 + threadIdx.x;
  if (i < n) {
    float d = (float)deg_i[i];
    ((float*)deg_i)[i] = rsqrtf(fmaxf(d, 1.0f));
  }
}

// ---------------- 3-phase hierarchical exclusive scan ----------------
// phase 1: per-1024-element block sums
__global__ __launch_bounds__(256) void k_scan_blk(const int* __restrict__ deg,
                                                  int* __restrict__ blksum, int N) {
  int t = threadIdx.x;
  int base = blockIdx.x * 1024 + t * 4;
  int4 v = {0, 0, 0, 0};
  if (base + 3 < N) v = *(const int4*)(deg + base);
  else {
    if (base < N) v.x = deg[base];
    if (base + 1 < N) v.y = deg[base + 1];
    if (base + 2 < N) v.z = deg[base + 2];
  }
  __shared__ int red[256];
  red[t] = v.x + v.y + v.z + v.w;
  __syncthreads();
  for (int off = 128; off > 0; off >>= 1) {
    if (t < off) red[t] += red[t + off];
    __syncthreads();
  }
  if (t == 0) blksum[blockIdx.x] = red[0];
}

// phase 2: exclusive scan of block sums (nb <= 256), in place
__global__ __launch_bounds__(256) void k_scan_top(int* __restrict__ blksum, int nb) {
  __shared__ int sh[256];
  int t = threadIdx.x;
  int v = (t < nb) ? blksum[t] : 0;
  sh[t] = v;
  __syncthreads();
  for (int off = 1; off < 256; off <<= 1) {
    int a = (t >= off) ? sh[t - off] : 0;
    __syncthreads();
    sh[t] += a;
    __syncthreads();
  }
  if (t < nb) blksum[t] = sh[t] - v;  // exclusive
}

// phase 3: local scan + block offset -> row_ptr (exclusive)
__global__ __launch_bounds__(256) void k_scan_add(const int* __restrict__ deg,
                                                  const int* __restrict__ blksum,
                                                  int* __restrict__ row_ptr, int N) {
  int t = threadIdx.x;
  int base = blockIdx.x * 1024 + t * 4;
  int4 v = {0, 0, 0, 0};
  if (base + 3 < N) v = *(const int4*)(deg + base);
  else {
    if (base < N) v.x = deg[base];
    if (base + 1 < N) v.y = deg[base + 1];
    if (base + 2 < N) v.z = deg[base + 2];
  }
  int s = v.x + v.y + v.z + v.w;
  __shared__ int sh[256];
  sh[t] = s;
  __syncthreads();
  for (int off = 1; off < 256; off <<= 1) {
    int a = (t >= off) ? sh[t - off] : 0;
    __syncthreads();
    sh[t] += a;
    __syncthreads();
  }
  int excl = sh[t] - s + blksum[blockIdx.x];
  if (base < N) row_ptr[base] = excl;
  if (base + 1 < N) row_ptr[base + 1] = excl + v.x;
  if (base + 2 < N) row_ptr[base + 2] = excl + v.x + v.y;
  if (base + 3 < N) row_ptr[base + 3] = excl + v.x + v.y + v.z;
}

// ---------------- bucket edges into CSR (mutates row_ptr to inclusive-end) --
__global__ __launch_bounds__(256) void k_bucket(const int* __restrict__ src,
                                                const int* __restrict__ dst,
                                                int* __restrict__ row_ptr,
                                                int* __restrict__ csr, int E) {
  int e = blockIdx.x * 256 + threadIdx.x;
  if (e < E) {
    int d = dst[e];
    int pos = atomicAdd(&row_ptr[d], 1);
    csr[pos] = src[e];
  }
}

// ---------------- GEMM: C[N x 128] = (scale[:,None] * A) @ W ----------------
// block = 256 threads, tile = 32 rows x 128 cols, thread = 4x4. Requires N%32==0.
__global__ __launch_bounds__(256) void k_gemm(const float* __restrict__ A,
                                              const float* __restrict__ W,
                                              const float* __restrict__ scale,
                                              float* __restrict__ C) {
  __shared__ float xs[32][D];
  const int r0 = blockIdx.x * 32;
  const int t = threadIdx.x;
  const float4* A4 = (const float4*)A;
  for (int idx = t; idx < 32 * 32; idx += 256) {
    int r = idx >> 5, c4 = idx & 31;
    float4 v = A4[(size_t)(r0 + r) * 32 + c4];
    float s = scale[r0 + r];
    v.x *= s; v.y *= s; v.z *= s; v.w *= s;
    *(float4*)&xs[r][c4 * 4] = v;
  }
  __syncthreads();
  const int jg = t & 31;
  const int rg = t >> 5;
  const float4* W4 = (const float4*)W;
  float acc[4][4];
#pragma unroll
  for (int r = 0; r < 4; ++r)
#pragma unroll
    for (int c = 0; c < 4; ++c) acc[r][c] = 0.0f;

  for (int k = 0; k < D; k += 4) {
    float4 a[4], w[4];
#pragma unroll
    for (int r = 0; r < 4; ++r) a[r] = *(const float4*)&xs[rg * 4 + r][k];
#pragma unroll
    for (int u = 0; u < 4; ++u) w[u] = W4[(size_t)(k + u) * 32 + jg];
#pragma unroll
    for (int r = 0; r < 4; ++r) {
      const float* ar = (const float*)&a[r];
#pragma unroll
      for (int u = 0; u < 4; ++u) {
        const float* wu = (const float*)&w[u];
#pragma unroll
        for (int c = 0; c < 4; ++c) acc[r][c] += ar[u] * wu[c];
      }
    }
  }
#pragma unroll
  for (int r = 0; r < 4; ++r) {
    float4 o;
    o.x = acc[r][0]; o.y = acc[r][1]; o.z = acc[r][2]; o.w = acc[r][3];
    *(float4*)&C[(size_t)(r0 + rg * 4 + r) * D + jg * 4] = o;
  }
}

// ---------------- gather SpMM + fused norm_dst/bias/relu ----------------
// one wave (64 lanes) per dst node; lane owns a float2 column slice.
__global__ __launch_bounds__(256) void k_gather(const float2* __restrict__ P,
                                                const int* __restrict__ row_ptr,
                                                const int* __restrict__ csr,
                                                const float* __restrict__ bias,
                                                float2* __restrict__ outH, int N) {
  int wid = (blockIdx.x * 256 + threadIdx.x) >> 6;
  if (wid >= N) return;
  int lane = threadIdx.x & 63;
  int end = row_ptr[wid];
  int start = (wid == 0) ? 0 : row_ptr[wid - 1];
  float2 acc = {0.0f, 0.0f};
  for (int base = start; base < end; base += 64) {
    int nb = min(64, end - base);
    int idx = (base + lane < end) ? csr[base + lane] : 0;
    int j = 0;
    for (; j + 4 <= nb; j += 4) {
      int s0 = __shfl(idx, j), s1 = __shfl(idx, j + 1);
      int s2 = __shfl(idx, j + 2), s3 = __shfl(idx, j + 3);
      float2 v0 = P[(size_t)s0 * 64 + lane];
      float2 v1 = P[(size_t)s1 * 64 + lane];
      float2 v2 = P[(size_t)s2 * 64 + lane];
      float2 v3 = P[(size_t)s3 * 64 + lane];
      acc.x += v0.x + v1.x + v2.x + v3.x;
      acc.y += v0.y + v1.y + v2.y + v3.y;
    }
    for (; j < nb; ++j) {
      int s = __shfl(idx, j);
      float2 v = P[(size_t)s * 64 + lane];
      acc.x += v.x;
      acc.y += v.y;
    }
  }
  float nd = rsqrtf(fmaxf((float)(end - start), 1.0f));
  float2 b = ((const float2*)bias)[lane];
  float2 o;
  o.x = fmaxf(acc.x * nd + b.x, 0.0f);
  o.y = fmaxf(acc.y * nd + b.y, 0.0f);
  outH[(size_t)wid * 64 + lane] = o;
}

// ---------------- per-graph node counts (LDS histogram, int) ----------------
__global__ __launch_bounds__(256) void k_counts(const int* __restrict__ gid,
                                                int* __restrict__ counts, int N) {
  __shared__ int h[64];
  if (threadIdx.x < 64) h[threadIdx.x] = 0;
  __syncthreads();
  int i = blockIdx.x * 256 + threadIdx.x;
  if (i < N) atomicAdd(&h[gid[i]], 1);
  __syncthreads();
  if (threadIdx.x < 64 && h[threadIdx.x] > 0)
    atomicAdd(&counts[threadIdx.x], h[threadIdx.x]);
}

// ---------------- graph_ptr = exclusive scan of counts (65 entries) ---------
__global__ __launch_bounds__(64) void k_gptr(const int* __restrict__ counts,
                                             int* __restrict__ gptr) {
  if (threadIdx.x == 0) {
    int run = 0;
    for (int g = 0; g < 64; ++g) {
      gptr[g] = run;
      run += counts[g];
    }
    gptr[64] = run;
  }
}

// ---------------- segment-sum pooling over sorted graph_id ----------------
__global__ __launch_bounds__(256) void k_pool(const float* __restrict__ H,
                                              const int* __restrict__ gptr,
                                              float* __restrict__ pool) {
  int g = blockIdx.x >> 3, chunk = blockIdx.x & 7;
  int col = threadIdx.x & 127, rpar = threadIdx.x >> 7;
  int s = gptr[g], e = gptr[g + 1];
  float acc = 0.0f;
  for (int r = s + chunk * 2 + rpar; r < e; r += 16)
    acc += H[(size_t)r * D + col];
  __shared__ float red[256];
  red[threadIdx.x] = acc;
  __syncthreads();
  if (rpar == 0) atomicAdd(&pool[g * D + col], acc + red[threadIdx.x + 128]);
}

// ---------------- readout MLP: out = relu(hg@Wr1+br1)@Wr2+br2 ----------------
__global__ __launch_bounds__(128) void k_readout(const float* __restrict__ pool,
                                                 const int* __restrict__ counts,
                                                 const float* __restrict__ Wr1,
                                                 const float* __restrict__ br1,
                                                 const float* __restrict__ Wr2,
                                                 const float* __restrict__ br2,
                                                 float* __restrict__ out) {
  int g = blockIdx.x;
  int j = threadIdx.x;
  __shared__ float hg[D];
  __shared__ float t1[D];
  float cnt = fmaxf((float)counts[g], 1.0f);
  hg[j] = pool[(size_t)g * D + j] / cnt;
  __syncthreads();
  float a = br1[j];
  for (int k = 0; k < D; ++k) a += hg[k] * Wr1[(size_t)k * D + j];
  t1[j] = fmaxf(a, 0.0f);
  __syncthreads();
  float b = br2[j];
  for (int k = 0; k < D; ++k) b += t1[k] * Wr2[(size_t)k * D + j];
  out[(size_t)g * D + j] = b;
}

extern "C" void kernel_launch(void* const* d_in, const int* in_sizes, int n_in,
                              void* d_out, int out_size, void* d_ws, size_t ws_size,
                              hipStream_t stream) {
  const float* x   = (const float*)d_in[0];
  const int* edge  = (const int*)d_in[1];
  const int* gid   = (const int*)d_in[2];
  const float* W1  = (const float*)d_in[4];
  const float* b1  = (const float*)d_in[5];
  const float* W2  = (const float*)d_in[6];
  const float* b2  = (const float*)d_in[7];
  const float* Wr1 = (const float*)d_in[8];
  const float* br1 = (const float*)d_in[9];
  const float* Wr2 = (const float*)d_in[10];
  const float* br2 = (const float*)d_in[11];

  const int N = in_sizes[0] / D;   // 100000
  const int E = in_sizes[1] / 2;   // 1600000
  const int* src = edge;
  const int* dst = edge + E;
  const int NB = (N + 1023) / 1024;  // scan blocks

  // workspace layout
  float* bufA   = (float*)d_ws;                   // N*128 (projection)
  float* bufB   = bufA + (size_t)N * D;           // N*128 (h1); first N ints = deg_in
  int* deg_in   = (int*)bufB;                     //   (consumed before gather1 writes)
  int* row_ptr  = (int*)(bufB + (size_t)N * D);   // N ints (mutated by bucket)
  int* csr      = row_ptr + N;                    // E ints
  int* deg_out  = csr + E;                        // N ints -> norm_src floats in place
  float* pool   = (float*)(deg_out + N);          // 64*128
  int* counts   = (int*)(pool + 64 * D);          // 64
  int* gptr     = counts + 64;                    // 65
  int* blksum   = gptr + 65;                      // NB ints (scan partials)
  size_t need = ((size_t)2 * N * D + 2 * N + E + 64 * D + 64 + 65 + NB) * sizeof(float);
  if (ws_size < need) return;

  float* out_g = (float*)d_out;      // 64*128
  float* h_out = out_g + 64 * D;     // N*128

  hipMemsetAsync(deg_out, 0, (size_t)N * sizeof(int), stream);
  hipMemsetAsync(deg_in, 0, (size_t)N * sizeof(int), stream);
  hipMemsetAsync(pool, 0, (64 * D + 64) * sizeof(float), stream);  // pool+counts

  // graph structure
  k_degree<<<(E + 255) / 256, 256, 0, stream>>>(src, dst, deg_out, deg_in, E);
  k_scan_blk<<<NB, 256, 0, stream>>>(deg_in, blksum, N);
  k_scan_top<<<1, 256, 0, stream>>>(blksum, NB);
  k_scan_add<<<NB, 256, 0, stream>>>(deg_in, blksum, row_ptr, N);
  k_bucket<<<(E + 255) / 256, 256, 0, stream>>>(src, dst, row_ptr, csr, E);
  k_norm<<<(N + 255) / 256, 256, 0, stream>>>(deg_out, N);
  const float* norm_src = (const float*)deg_out;

  // layer 1
  k_gemm<<<N / 32, 256, 0, stream>>>(x, W1, norm_src, bufA);
  k_gather<<<(N * 64 + 255) / 256, 256, 0, stream>>>(
      (const float2*)bufA, row_ptr, csr, b1, (float2*)bufB, N);

  // layer 2 (gather writes straight into d_out's h region)
  k_gemm<<<N / 32, 256, 0, stream>>>(bufB, W2, norm_src, bufA);
  k_gather<<<(N * 64 + 255) / 256, 256, 0, stream>>>(
      (const float2*)bufA, row_ptr, csr, b2, (float2*)h_out, N);

  // pooling + readout
  k_counts<<<(N + 255) / 256, 256, 0, stream>>>(gid, counts, N);
  k_gptr<<<1, 64, 0, stream>>>(counts, gptr);
  k_pool<<<64 * 8, 256, 0, stream>>>(h_out, gptr, pool);
  k_readout<<<64, 128, 0, stream>>>(pool, counts, Wr1, br1, Wr2, br2, out_g);
}

// Round 4
// 590.695 us; speedup vs baseline: 10.6096x; 1.2803x over previous
//
#include <hip/hip_runtime.h>
#include <math.h>

// GCN: h1 = relu(norm_dst * A * (norm_src * x) @ W1 + b1)
//      h2 = relu(norm_dst * A * (norm_src * h1) @ W2 + b2)
//      hg = mean_per_graph(h2); out = relu(hg@Wr1+br1)@Wr2+br2
// d_out = [out (64*128) | h2 (N*128)]
//
// R2: scatter-atomic SpMM -> CSR-by-dst + register gather (fused norm/bias/relu).
// R3: single-block scan -> 3-phase hierarchical scan.
// R4: degree/bucket random device atomics (4.8M RMW = 150MB write-through HBM,
//     ~220us) -> two-level counting sort: LDS-aggregated coarse histogram
//     (196 buckets of 512 nodes), coarse scatter of packed edges, per-bucket
//     fine LDS histogram producing row_end + CSR (dst side) and norm_src
//     (src side). Only ~200k contended global atomics remain.
// Assumes N <= 131072 (src fits 17 bits in packing).

#define D 128
#define BSH 9
#define BSZ 512

// ---------------- coarse histogram (dst>>9 and src>>9) ----------------
__global__ __launch_bounds__(256) void k_coarse(const int* __restrict__ src,
                                                const int* __restrict__ dst,
                                                int* __restrict__ cnt_d,
                                                int* __restrict__ cnt_s,
                                                int E, int nbkt) {
  __shared__ int hd[256], hs[256];
  int t = threadIdx.x;
  hd[t] = 0; hs[t] = 0;
  __syncthreads();
  int chunk = (E + gridDim.x - 1) / gridDim.x;
  int lo = blockIdx.x * chunk, hi = min(lo + chunk, E);
  for (int e = lo + t; e < hi; e += 256) {
    atomicAdd(&hd[dst[e] >> BSH], 1);
    atomicAdd(&hs[src[e] >> BSH], 1);
  }
  __syncthreads();
  if (t < nbkt) {
    if (hd[t]) atomicAdd(&cnt_d[t], hd[t]);
    if (hs[t]) atomicAdd(&cnt_s[t], hs[t]);
  }
}

// ---------------- scan coarse counts -> bucket ptrs + cursors ----------------
__global__ __launch_bounds__(256) void k_cscan(const int* __restrict__ cnt_d,
                                               const int* __restrict__ cnt_s,
                                               int* __restrict__ ptr_d,
                                               int* __restrict__ cur_d,
                                               int* __restrict__ ptr_s,
                                               int* __restrict__ cur_s,
                                               int nbkt, int E) {
  __shared__ int sh[256];
  int t = threadIdx.x;
  int v = (t < nbkt) ? cnt_d[t] : 0;
  sh[t] = v;
  __syncthreads();
  for (int off = 1; off < 256; off <<= 1) {
    int a = (t >= off) ? sh[t - off] : 0;
    __syncthreads();
    sh[t] += a;
    __syncthreads();
  }
  if (t < nbkt) { int ex = sh[t] - v; ptr_d[t] = ex; cur_d[t] = ex; }
  if (t == 0) ptr_d[nbkt] = E;
  __syncthreads();
  v = (t < nbkt) ? cnt_s[t] : 0;
  sh[t] = v;
  __syncthreads();
  for (int off = 1; off < 256; off <<= 1) {
    int a = (t >= off) ? sh[t - off] : 0;
    __syncthreads();
    sh[t] += a;
    __syncthreads();
  }
  if (t < nbkt) { int ex = sh[t] - v; ptr_s[t] = ex; cur_s[t] = ex; }
  if (t == 0) ptr_s[nbkt] = E;
}

// ---------------- coarse scatter: packed edges into buckets ----------------
// packed_d: (dst_low9 << 17) | src   (by dst bucket)
// packed_s: src_low9                 (by src bucket)
__global__ __launch_bounds__(256) void k_cscatter(const int* __restrict__ src,
                                                  const int* __restrict__ dst,
                                                  int* __restrict__ cur_d,
                                                  int* __restrict__ cur_s,
                                                  int* __restrict__ packed_d,
                                                  int* __restrict__ packed_s,
                                                  int E, int nbkt) {
  __shared__ int hd[256], hs[256], bd[256], bs2[256];
  int t = threadIdx.x;
  hd[t] = 0; hs[t] = 0;
  __syncthreads();
  int chunk = (E + gridDim.x - 1) / gridDim.x;
  int lo = blockIdx.x * chunk, hi = min(lo + chunk, E);
  for (int e = lo + t; e < hi; e += 256) {
    atomicAdd(&hd[dst[e] >> BSH], 1);
    atomicAdd(&hs[src[e] >> BSH], 1);
  }
  __syncthreads();
  if (t < nbkt) {
    bd[t] = hd[t] ? atomicAdd(&cur_d[t], hd[t]) : 0;
    bs2[t] = hs[t] ? atomicAdd(&cur_s[t], hs[t]) : 0;
  }
  __syncthreads();
  hd[t] = 0; hs[t] = 0;
  __syncthreads();
  for (int e = lo + t; e < hi; e += 256) {
    int s = src[e], d = dst[e];
    int b1 = d >> BSH;
    int r1 = atomicAdd(&hd[b1], 1);
    packed_d[bd[b1] + r1] = ((d & (BSZ - 1)) << 17) | s;
    int b2 = s >> BSH;
    int r2 = atomicAdd(&hs[b2], 1);
    packed_s[bs2[b2] + r2] = s & (BSZ - 1);
  }
}

// ---------------- fine pass (dst): row_end + CSR ----------------
__global__ __launch_bounds__(256) void k_fine_dst(const int* __restrict__ packed_d,
                                                  const int* __restrict__ ptr_d,
                                                  int* __restrict__ row_end,
                                                  int* __restrict__ csr, int N) {
  __shared__ int hist[512], excl[512], ps[256];
  int b = blockIdx.x, t = threadIdx.x;
  int lo = ptr_d[b], hi = ptr_d[b + 1];
  hist[t] = 0; hist[t + 256] = 0;
  __syncthreads();
  for (int e = lo + t; e < hi; e += 256)
    atomicAdd(&hist[packed_d[e] >> 17], 1);
  __syncthreads();
  int a0 = hist[2 * t], a1 = hist[2 * t + 1];
  ps[t] = a0 + a1;
  __syncthreads();
  for (int off = 1; off < 256; off <<= 1) {
    int a = (t >= off) ? ps[t - off] : 0;
    __syncthreads();
    ps[t] += a;
    __syncthreads();
  }
  int exc = ps[t] - (a0 + a1);
  excl[2 * t] = exc;
  excl[2 * t + 1] = exc + a0;
  int nbase = b << BSH;
  if (nbase + 2 * t < N)     row_end[nbase + 2 * t]     = lo + exc + a0;
  if (nbase + 2 * t + 1 < N) row_end[nbase + 2 * t + 1] = lo + exc + a0 + a1;
  __syncthreads();
  hist[t] = 0; hist[t + 256] = 0;
  __syncthreads();
  for (int e = lo + t; e < hi; e += 256) {
    int p = packed_d[e];
    int dlow = p >> 17, s = p & 0x1FFFF;
    int r = atomicAdd(&hist[dlow], 1);
    csr[lo + excl[dlow] + r] = s;
  }
}

// ---------------- fine pass (src): norm_src = rsqrt(max(deg_out,1)) ----------
__global__ __launch_bounds__(256) void k_fine_src(const int* __restrict__ packed_s,
                                                  const int* __restrict__ ptr_s,
                                                  float* __restrict__ norm_src, int N) {
  __shared__ int hist[512];
  int b = blockIdx.x, t = threadIdx.x;
  int lo = ptr_s[b], hi = ptr_s[b + 1];
  hist[t] = 0; hist[t + 256] = 0;
  __syncthreads();
  for (int e = lo + t; e < hi; e += 256)
    atomicAdd(&hist[packed_s[e]], 1);
  __syncthreads();
  int nbase = b << BSH;
  for (int i = t; i < BSZ; i += 256)
    if (nbase + i < N)
      norm_src[nbase + i] = rsqrtf(fmaxf((float)hist[i], 1.0f));
}

// ---------------- GEMM: C[N x 128] = (scale[:,None] * A) @ W ----------------
__global__ __launch_bounds__(256) void k_gemm(const float* __restrict__ A,
                                              const float* __restrict__ W,
                                              const float* __restrict__ scale,
                                              float* __restrict__ C) {
  __shared__ float xs[32][D];
  const int r0 = blockIdx.x * 32;
  const int t = threadIdx.x;
  const float4* A4 = (const float4*)A;
  for (int idx = t; idx < 32 * 32; idx += 256) {
    int r = idx >> 5, c4 = idx & 31;
    float4 v = A4[(size_t)(r0 + r) * 32 + c4];
    float s = scale[r0 + r];
    v.x *= s; v.y *= s; v.z *= s; v.w *= s;
    *(float4*)&xs[r][c4 * 4] = v;
  }
  __syncthreads();
  const int jg = t & 31;
  const int rg = t >> 5;
  const float4* W4 = (const float4*)W;
  float acc[4][4];
#pragma unroll
  for (int r = 0; r < 4; ++r)
#pragma unroll
    for (int c = 0; c < 4; ++c) acc[r][c] = 0.0f;

  for (int k = 0; k < D; k += 4) {
    float4 a[4], w[4];
#pragma unroll
    for (int r = 0; r < 4; ++r) a[r] = *(const float4*)&xs[rg * 4 + r][k];
#pragma unroll
    for (int u = 0; u < 4; ++u) w[u] = W4[(size_t)(k + u) * 32 + jg];
#pragma unroll
    for (int r = 0; r < 4; ++r) {
      const float* ar = (const float*)&a[r];
#pragma unroll
      for (int u = 0; u < 4; ++u) {
        const float* wu = (const float*)&w[u];
#pragma unroll
        for (int c = 0; c < 4; ++c) acc[r][c] += ar[u] * wu[c];
      }
    }
  }
#pragma unroll
  for (int r = 0; r < 4; ++r) {
    float4 o;
    o.x = acc[r][0]; o.y = acc[r][1]; o.z = acc[r][2]; o.w = acc[r][3];
    *(float4*)&C[(size_t)(r0 + rg * 4 + r) * D + jg * 4] = o;
  }
}

// ---------------- gather SpMM + fused norm_dst/bias/relu ----------------
// one wave per dst node; row_end[n] = end, start = row_end[n-1] (0 for n=0).
__global__ __launch_bounds__(256) void k_gather(const float2* __restrict__ P,
                                                const int* __restrict__ row_end,
                                                const int* __restrict__ csr,
                                                const float* __restrict__ bias,
                                                float2* __restrict__ outH, int N) {
  int wid = (blockIdx.x * 256 + threadIdx.x) >> 6;
  if (wid >= N) return;
  int lane = threadIdx.x & 63;
  int end = row_end[wid];
  int start = (wid == 0) ? 0 : row_end[wid - 1];
  float2 acc = {0.0f, 0.0f};
  for (int base = start; base < end; base += 64) {
    int nb = min(64, end - base);
    int idx = (base + lane < end) ? csr[base + lane] : 0;
    int j = 0;
    for (; j + 4 <= nb; j += 4) {
      int s0 = __shfl(idx, j), s1 = __shfl(idx, j + 1);
      int s2 = __shfl(idx, j + 2), s3 = __shfl(idx, j + 3);
      float2 v0 = P[(size_t)s0 * 64 + lane];
      float2 v1 = P[(size_t)s1 * 64 + lane];
      float2 v2 = P[(size_t)s2 * 64 + lane];
      float2 v3 = P[(size_t)s3 * 64 + lane];
      acc.x += v0.x + v1.x + v2.x + v3.x;
      acc.y += v0.y + v1.y + v2.y + v3.y;
    }
    for (; j < nb; ++j) {
      int s = __shfl(idx, j);
      float2 v = P[(size_t)s * 64 + lane];
      acc.x += v.x;
      acc.y += v.y;
    }
  }
  float nd = rsqrtf(fmaxf((float)(end - start), 1.0f));
  float2 b = ((const float2*)bias)[lane];
  float2 o;
  o.x = fmaxf(acc.x * nd + b.x, 0.0f);
  o.y = fmaxf(acc.y * nd + b.y, 0.0f);
  outH[(size_t)wid * 64 + lane] = o;
}

// ---------------- per-graph node counts (LDS histogram, int) ----------------
__global__ __launch_bounds__(256) void k_counts(const int* __restrict__ gid,
                                                int* __restrict__ counts, int N) {
  __shared__ int h[64];
  if (threadIdx.x < 64) h[threadIdx.x] = 0;
  __syncthreads();
  int i = blockIdx.x * 256 + threadIdx.x;
  if (i < N) atomicAdd(&h[gid[i]], 1);
  __syncthreads();
  if (threadIdx.x < 64 && h[threadIdx.x] > 0)
    atomicAdd(&counts[threadIdx.x], h[threadIdx.x]);
}

// ---------------- graph_ptr = exclusive scan of counts (65 entries) ---------
__global__ __launch_bounds__(64) void k_gptr(const int* __restrict__ counts,
                                             int* __restrict__ gptr) {
  if (threadIdx.x == 0) {
    int run = 0;
    for (int g = 0; g < 64; ++g) {
      gptr[g] = run;
      run += counts[g];
    }
    gptr[64] = run;
  }
}

// ---------------- segment-sum pooling over sorted graph_id ----------------
__global__ __launch_bounds__(256) void k_pool(const float* __restrict__ H,
                                              const int* __restrict__ gptr,
                                              float* __restrict__ pool) {
  int g = blockIdx.x >> 3, chunk = blockIdx.x & 7;
  int col = threadIdx.x & 127, rpar = threadIdx.x >> 7;
  int s = gptr[g], e = gptr[g + 1];
  float acc = 0.0f;
  for (int r = s + chunk * 2 + rpar; r < e; r += 16)
    acc += H[(size_t)r * D + col];
  __shared__ float red[256];
  red[threadIdx.x] = acc;
  __syncthreads();
  if (rpar == 0) atomicAdd(&pool[g * D + col], acc + red[threadIdx.x + 128]);
}

// ---------------- readout MLP ----------------
__global__ __launch_bounds__(128) void k_readout(const float* __restrict__ pool,
                                                 const int* __restrict__ counts,
                                                 const float* __restrict__ Wr1,
                                                 const float* __restrict__ br1,
                                                 const float* __restrict__ Wr2,
                                                 const float* __restrict__ br2,
                                                 float* __restrict__ out) {
  int g = blockIdx.x;
  int j = threadIdx.x;
  __shared__ float hg[D];
  __shared__ float t1[D];
  float cnt = fmaxf((float)counts[g], 1.0f);
  hg[j] = pool[(size_t)g * D + j] / cnt;
  __syncthreads();
  float a = br1[j];
  for (int k = 0; k < D; ++k) a += hg[k] * Wr1[(size_t)k * D + j];
  t1[j] = fmaxf(a, 0.0f);
  __syncthreads();
  float b = br2[j];
  for (int k = 0; k < D; ++k) b += t1[k] * Wr2[(size_t)k * D + j];
  out[(size_t)g * D + j] = b;
}

extern "C" void kernel_launch(void* const* d_in, const int* in_sizes, int n_in,
                              void* d_out, int out_size, void* d_ws, size_t ws_size,
                              hipStream_t stream) {
  const float* x   = (const float*)d_in[0];
  const int* edge  = (const int*)d_in[1];
  const int* gid   = (const int*)d_in[2];
  const float* W1  = (const float*)d_in[4];
  const float* b1  = (const float*)d_in[5];
  const float* W2  = (const float*)d_in[6];
  const float* b2  = (const float*)d_in[7];
  const float* Wr1 = (const float*)d_in[8];
  const float* br1 = (const float*)d_in[9];
  const float* Wr2 = (const float*)d_in[10];
  const float* br2 = (const float*)d_in[11];

  const int N = in_sizes[0] / D;   // 100000
  const int E = in_sizes[1] / 2;   // 1600000
  const int* src = edge;
  const int* dst = edge + E;
  const int nbkt = (N + BSZ - 1) >> BSH;  // 196

  // workspace layout
  float* bufA     = (float*)d_ws;                    // N*128 (projection)
  float* bufB     = bufA + (size_t)N * D;            // N*128 (h1)
  int* row_end    = (int*)(bufB + (size_t)N * D);    // N
  int* csr        = row_end + N;                     // E
  float* norm_src = (float*)(csr + E);               // N
  float* pool     = norm_src + N;                    // 64*128
  int* counts     = (int*)(pool + 64 * D);           // 64
  int* gptr       = counts + 64;                     // 65
  int* cnt_d      = gptr + 65;                       // 256
  int* cnt_s      = cnt_d + 256;                     // 256
  int* ptr_d      = cnt_s + 256;                     // 257
  int* ptr_s      = ptr_d + 257;                     // 257
  int* cur_d      = ptr_s + 257;                     // 256
  int* cur_s      = cur_d + 256;                     // 256
  // temporary packed edge arrays alias bufA (consumed before gemm1 writes it)
  int* packed_d   = (int*)bufA;                      // E
  int* packed_s   = packed_d + E;                    // E  (2E ints << N*128 floats)
  size_t need = ((size_t)2 * N * D + 2 * N + E + 64 * D + 64 + 65 + 1538) * sizeof(float);
  if (ws_size < need) return;

  float* out_g = (float*)d_out;      // 64*128
  float* h_out = out_g + 64 * D;     // N*128

  hipMemsetAsync(cnt_d, 0, 512 * sizeof(int), stream);              // cnt_d + cnt_s
  hipMemsetAsync(pool, 0, (64 * D + 64) * sizeof(float), stream);   // pool + counts

  // graph structure via two-level counting sort (no random global atomics)
  k_coarse<<<256, 256, 0, stream>>>(src, dst, cnt_d, cnt_s, E, nbkt);
  k_cscan<<<1, 256, 0, stream>>>(cnt_d, cnt_s, ptr_d, cur_d, ptr_s, cur_s, nbkt, E);
  k_cscatter<<<256, 256, 0, stream>>>(src, dst, cur_d, cur_s, packed_d, packed_s, E, nbkt);
  k_fine_dst<<<nbkt, 256, 0, stream>>>(packed_d, ptr_d, row_end, csr, N);
  k_fine_src<<<nbkt, 256, 0, stream>>>(packed_s, ptr_s, norm_src, N);

  // layer 1
  k_gemm<<<N / 32, 256, 0, stream>>>(x, W1, norm_src, bufA);
  k_gather<<<(N * 64 + 255) / 256, 256, 0, stream>>>(
      (const float2*)bufA, row_end, csr, b1, (float2*)bufB, N);

  // layer 2 (gather writes straight into d_out's h region)
  k_gemm<<<N / 32, 256, 0, stream>>>(bufB, W2, norm_src, bufA);
  k_gather<<<(N * 64 + 255) / 256, 256, 0, stream>>>(
      (const float2*)bufA, row_end, csr, b2, (float2*)h_out, N);

  // pooling + readout
  k_counts<<<(N + 255) / 256, 256, 0, stream>>>(gid, counts, N);
  k_gptr<<<1, 64, 0, stream>>>(counts, gptr);
  k_pool<<<64 * 8, 256, 0, stream>>>(h_out, gptr, pool);
  k_readout<<<64, 128, 0, stream>>>(pool, counts, Wr1, br1, Wr2, br2, out_g);
}

// Round 5
// 442.254 us; speedup vs baseline: 14.1707x; 1.3356x over previous
//
#include <hip/hip_runtime.h>
#include <math.h>

// GCN: h1 = relu(norm_dst * A * (norm_src * x) @ W1 + b1)
//      h2 = relu(norm_dst * A * (norm_src * h1) @ W2 + b2)
//      hg = mean_per_graph(h2); out = relu(hg@Wr1+br1)@Wr2+br2
// d_out = [out (64*128) | h2 (N*128)]
//
// R2: scatter-atomic SpMM -> CSR-by-dst + register gather (fused norm/bias/relu).
// R3: single-block scan -> 3-phase hierarchical scan.
// R4: degree/bucket random atomics -> two-level counting sort (LDS histograms).
// R5: fp16 projection pipeline: GEMMs via mfma_f32_16x16x32_f16 (fp32 accum),
//     P and h1' stored fp16 (gather row 512B -> 256B), gather-1 pre-multiplies
//     norm_src so GEMM-2 stages without conversion. fp16 (not bf16) keeps
//     rounding ~4x tighter; all magnitudes O(1) so no range risk.
// Assumes N <= 131072 (src fits 17 bits in packing).

#define D 128
#define BSH 9
#define BSZ 512

typedef _Float16 half8 __attribute__((ext_vector_type(8)));
typedef _Float16 half4v __attribute__((ext_vector_type(4)));
typedef _Float16 half2v __attribute__((ext_vector_type(2)));
typedef float f32x4 __attribute__((ext_vector_type(4)));

// ---------------- coarse histogram (dst>>9 and src>>9) ----------------
__global__ __launch_bounds__(256) void k_coarse(const int* __restrict__ src,
                                                const int* __restrict__ dst,
                                                int* __restrict__ cnt_d,
                                                int* __restrict__ cnt_s,
                                                int E, int nbkt) {
  __shared__ int hd[256], hs[256];
  int t = threadIdx.x;
  hd[t] = 0; hs[t] = 0;
  __syncthreads();
  int chunk = (E + gridDim.x - 1) / gridDim.x;
  int lo = blockIdx.x * chunk, hi = min(lo + chunk, E);
  for (int e = lo + t; e < hi; e += 256) {
    atomicAdd(&hd[dst[e] >> BSH], 1);
    atomicAdd(&hs[src[e] >> BSH], 1);
  }
  __syncthreads();
  if (t < nbkt) {
    if (hd[t]) atomicAdd(&cnt_d[t], hd[t]);
    if (hs[t]) atomicAdd(&cnt_s[t], hs[t]);
  }
}

// ---------------- scan coarse counts -> bucket ptrs + cursors ----------------
__global__ __launch_bounds__(256) void k_cscan(const int* __restrict__ cnt_d,
                                               const int* __restrict__ cnt_s,
                                               int* __restrict__ ptr_d,
                                               int* __restrict__ cur_d,
                                               int* __restrict__ ptr_s,
                                               int* __restrict__ cur_s,
                                               int nbkt, int E) {
  __shared__ int sh[256];
  int t = threadIdx.x;
  int v = (t < nbkt) ? cnt_d[t] : 0;
  sh[t] = v;
  __syncthreads();
  for (int off = 1; off < 256; off <<= 1) {
    int a = (t >= off) ? sh[t - off] : 0;
    __syncthreads();
    sh[t] += a;
    __syncthreads();
  }
  if (t < nbkt) { int ex = sh[t] - v; ptr_d[t] = ex; cur_d[t] = ex; }
  if (t == 0) ptr_d[nbkt] = E;
  __syncthreads();
  v = (t < nbkt) ? cnt_s[t] : 0;
  sh[t] = v;
  __syncthreads();
  for (int off = 1; off < 256; off <<= 1) {
    int a = (t >= off) ? sh[t - off] : 0;
    __syncthreads();
    sh[t] += a;
    __syncthreads();
  }
  if (t < nbkt) { int ex = sh[t] - v; ptr_s[t] = ex; cur_s[t] = ex; }
  if (t == 0) ptr_s[nbkt] = E;
}

// ---------------- coarse scatter: packed edges into buckets ----------------
__global__ __launch_bounds__(256) void k_cscatter(const int* __restrict__ src,
                                                  const int* __restrict__ dst,
                                                  int* __restrict__ cur_d,
                                                  int* __restrict__ cur_s,
                                                  int* __restrict__ packed_d,
                                                  int* __restrict__ packed_s,
                                                  int E, int nbkt) {
  __shared__ int hd[256], hs[256], bd[256], bs2[256];
  int t = threadIdx.x;
  hd[t] = 0; hs[t] = 0;
  __syncthreads();
  int chunk = (E + gridDim.x - 1) / gridDim.x;
  int lo = blockIdx.x * chunk, hi = min(lo + chunk, E);
  for (int e = lo + t; e < hi; e += 256) {
    atomicAdd(&hd[dst[e] >> BSH], 1);
    atomicAdd(&hs[src[e] >> BSH], 1);
  }
  __syncthreads();
  if (t < nbkt) {
    bd[t] = hd[t] ? atomicAdd(&cur_d[t], hd[t]) : 0;
    bs2[t] = hs[t] ? atomicAdd(&cur_s[t], hs[t]) : 0;
  }
  __syncthreads();
  hd[t] = 0; hs[t] = 0;
  __syncthreads();
  for (int e = lo + t; e < hi; e += 256) {
    int s = src[e], d = dst[e];
    int b1 = d >> BSH;
    int r1 = atomicAdd(&hd[b1], 1);
    packed_d[bd[b1] + r1] = ((d & (BSZ - 1)) << 17) | s;
    int b2 = s >> BSH;
    int r2 = atomicAdd(&hs[b2], 1);
    packed_s[bs2[b2] + r2] = s & (BSZ - 1);
  }
}

// ---------------- fine pass (dst): row_end + CSR ----------------
__global__ __launch_bounds__(256) void k_fine_dst(const int* __restrict__ packed_d,
                                                  const int* __restrict__ ptr_d,
                                                  int* __restrict__ row_end,
                                                  int* __restrict__ csr, int N) {
  __shared__ int hist[512], excl[512], ps[256];
  int b = blockIdx.x, t = threadIdx.x;
  int lo = ptr_d[b], hi = ptr_d[b + 1];
  hist[t] = 0; hist[t + 256] = 0;
  __syncthreads();
  for (int e = lo + t; e < hi; e += 256)
    atomicAdd(&hist[packed_d[e] >> 17], 1);
  __syncthreads();
  int a0 = hist[2 * t], a1 = hist[2 * t + 1];
  ps[t] = a0 + a1;
  __syncthreads();
  for (int off = 1; off < 256; off <<= 1) {
    int a = (t >= off) ? ps[t - off] : 0;
    __syncthreads();
    ps[t] += a;
    __syncthreads();
  }
  int exc = ps[t] - (a0 + a1);
  excl[2 * t] = exc;
  excl[2 * t + 1] = exc + a0;
  int nbase = b << BSH;
  if (nbase + 2 * t < N)     row_end[nbase + 2 * t]     = lo + exc + a0;
  if (nbase + 2 * t + 1 < N) row_end[nbase + 2 * t + 1] = lo + exc + a0 + a1;
  __syncthreads();
  hist[t] = 0; hist[t + 256] = 0;
  __syncthreads();
  for (int e = lo + t; e < hi; e += 256) {
    int p = packed_d[e];
    int dlow = p >> 17, s = p & 0x1FFFF;
    int r = atomicAdd(&hist[dlow], 1);
    csr[lo + excl[dlow] + r] = s;
  }
}

// ---------------- fine pass (src): norm_src = rsqrt(max(deg_out,1)) ----------
__global__ __launch_bounds__(256) void k_fine_src(const int* __restrict__ packed_s,
                                                  const int* __restrict__ ptr_s,
                                                  float* __restrict__ norm_src, int N) {
  __shared__ int hist[512];
  int b = blockIdx.x, t = threadIdx.x;
  int lo = ptr_s[b], hi = ptr_s[b + 1];
  hist[t] = 0; hist[t + 256] = 0;
  __syncthreads();
  for (int e = lo + t; e < hi; e += 256)
    atomicAdd(&hist[packed_s[e]], 1);
  __syncthreads();
  int nbase = b << BSH;
  for (int i = t; i < BSZ; i += 256)
    if (nbase + i < N)
      norm_src[nbase + i] = rsqrtf(fmaxf((float)hist[i], 1.0f));
}

// ---------------- prep: Wt[n][k] = (half)W[k][n] for W1,W2 ----------------
__global__ __launch_bounds__(256) void k_prep(const float* __restrict__ W1,
                                              const float* __restrict__ W2,
                                              _Float16* __restrict__ Wt1,
                                              _Float16* __restrict__ Wt2) {
  int idx = blockIdx.x * 256 + threadIdx.x;   // grid 128 -> 32768 threads
  int m = idx >> 14;
  int i = idx & 16383;
  int k = i >> 7, n = i & 127;
  const float* W = m ? W2 : W1;
  _Float16* Wt = m ? Wt2 : Wt1;
  Wt[n * 128 + k] = (_Float16)W[i];  // i == k*128+n
}

// ---------------- MFMA GEMM (fp32 input): C(half) = (scale*A)@W ----------------
// block 256 = 4 waves; tile 64 rows x 128 cols; K=128.
__global__ __launch_bounds__(256) void k_gemm1(const float* __restrict__ A,
                                               const _Float16* __restrict__ Wt,
                                               const float* __restrict__ scale,
                                               _Float16* __restrict__ C, int N) {
  __shared__ _Float16 As[64][136];
  __shared__ _Float16 Cs[64][128];
  const int r0 = blockIdx.x * 64;
  const int t = threadIdx.x;
  for (int i = t; i < 64 * 32; i += 256) {
    int r = i >> 5, c4 = i & 31;
    float4 v = {0.f, 0.f, 0.f, 0.f};
    if (r0 + r < N) {
      v = ((const float4*)A)[(size_t)(r0 + r) * 32 + c4];
      float s = scale[r0 + r];
      v.x *= s; v.y *= s; v.z *= s; v.w *= s;
    }
    half4v h = {(_Float16)v.x, (_Float16)v.y, (_Float16)v.z, (_Float16)v.w};
    *(half4v*)&As[r][c4 * 4] = h;
  }
  __syncthreads();
  const int w = t >> 6, l = t & 63;
  const int c = l & 15, quad = l >> 4;
  f32x4 acc[8];
#pragma unroll
  for (int nt = 0; nt < 8; ++nt) acc[nt] = (f32x4){0.f, 0.f, 0.f, 0.f};
#pragma unroll
  for (int kc = 0; kc < 4; ++kc) {
    half8 a = *(const half8*)&As[w * 16 + c][kc * 32 + quad * 8];
#pragma unroll
    for (int nt = 0; nt < 8; ++nt) {
      half8 b = *(const half8*)&Wt[(size_t)(nt * 16 + c) * 128 + kc * 32 + quad * 8];
      acc[nt] = __builtin_amdgcn_mfma_f32_16x16x32_f16(a, b, acc[nt], 0, 0, 0);
    }
  }
#pragma unroll
  for (int nt = 0; nt < 8; ++nt)
#pragma unroll
    for (int r = 0; r < 4; ++r)
      Cs[w * 16 + quad * 4 + r][nt * 16 + c] = (_Float16)acc[nt][r];
  __syncthreads();
  for (int i = t; i < 64 * 16; i += 256) {
    int r = i >> 4, c8 = i & 15;
    if (r0 + r < N)
      ((half8*)C)[(size_t)(r0 + r) * 16 + c8] = *(half8*)&Cs[r][c8 * 8];
  }
}

// ---------------- MFMA GEMM (fp16 pre-scaled input): C(half) = A@W -----------
__global__ __launch_bounds__(256) void k_gemm2(const _Float16* __restrict__ A,
                                               const _Float16* __restrict__ Wt,
                                               _Float16* __restrict__ C, int N) {
  __shared__ _Float16 As[64][136];
  __shared__ _Float16 Cs[64][128];
  const int r0 = blockIdx.x * 64;
  const int t = threadIdx.x;
  for (int i = t; i < 64 * 16; i += 256) {
    int r = i >> 4, c8 = i & 15;
    half8 v = {0, 0, 0, 0, 0, 0, 0, 0};
    if (r0 + r < N) v = ((const half8*)A)[(size_t)(r0 + r) * 16 + c8];
    *(half8*)&As[r][c8 * 8] = v;
  }
  __syncthreads();
  const int w = t >> 6, l = t & 63;
  const int c = l & 15, quad = l >> 4;
  f32x4 acc[8];
#pragma unroll
  for (int nt = 0; nt < 8; ++nt) acc[nt] = (f32x4){0.f, 0.f, 0.f, 0.f};
#pragma unroll
  for (int kc = 0; kc < 4; ++kc) {
    half8 a = *(const half8*)&As[w * 16 + c][kc * 32 + quad * 8];
#pragma unroll
    for (int nt = 0; nt < 8; ++nt) {
      half8 b = *(const half8*)&Wt[(size_t)(nt * 16 + c) * 128 + kc * 32 + quad * 8];
      acc[nt] = __builtin_amdgcn_mfma_f32_16x16x32_f16(a, b, acc[nt], 0, 0, 0);
    }
  }
#pragma unroll
  for (int nt = 0; nt < 8; ++nt)
#pragma unroll
    for (int r = 0; r < 4; ++r)
      Cs[w * 16 + quad * 4 + r][nt * 16 + c] = (_Float16)acc[nt][r];
  __syncthreads();
  for (int i = t; i < 64 * 16; i += 256) {
    int r = i >> 4, c8 = i & 15;
    if (r0 + r < N)
      ((half8*)C)[(size_t)(r0 + r) * 16 + c8] = *(half8*)&Cs[r][c8 * 8];
  }
}

// ---------------- gather 1: h1' = norm_src * relu(agg*nd + b), fp16 out ------
__global__ __launch_bounds__(256) void k_gather1(const _Float16* __restrict__ P,
                                                 const int* __restrict__ row_end,
                                                 const int* __restrict__ csr,
                                                 const float* __restrict__ bias,
                                                 const float* __restrict__ norm_src,
                                                 _Float16* __restrict__ outH, int N) {
  int wid = (blockIdx.x * 256 + threadIdx.x) >> 6;
  if (wid >= N) return;
  int lane = threadIdx.x & 63;
  int end = row_end[wid];
  int start = (wid == 0) ? 0 : row_end[wid - 1];
  float ax = 0.f, ay = 0.f;
  const half2v* P2 = (const half2v*)P;
  for (int base = start; base < end; base += 64) {
    int nb = min(64, end - base);
    int idx = (base + lane < end) ? csr[base + lane] : 0;
    int j = 0;
    for (; j + 4 <= nb; j += 4) {
      int s0 = __shfl(idx, j), s1 = __shfl(idx, j + 1);
      int s2 = __shfl(idx, j + 2), s3 = __shfl(idx, j + 3);
      half2v v0 = P2[(size_t)s0 * 64 + lane];
      half2v v1 = P2[(size_t)s1 * 64 + lane];
      half2v v2 = P2[(size_t)s2 * 64 + lane];
      half2v v3 = P2[(size_t)s3 * 64 + lane];
      ax += (float)v0.x + (float)v1.x + (float)v2.x + (float)v3.x;
      ay += (float)v0.y + (float)v1.y + (float)v2.y + (float)v3.y;
    }
    for (; j < nb; ++j) {
      int s = __shfl(idx, j);
      half2v v = P2[(size_t)s * 64 + lane];
      ax += (float)v.x; ay += (float)v.y;
    }
  }
  float nd = rsqrtf(fmaxf((float)(end - start), 1.0f));
  float ns = norm_src[wid];
  float2 b = ((const float2*)bias)[lane];
  half2v o = {(_Float16)(fmaxf(ax * nd + b.x, 0.f) * ns),
              (_Float16)(fmaxf(ay * nd + b.y, 0.f) * ns)};
  ((half2v*)outH)[(size_t)wid * 64 + lane] = o;
}

// ---------------- gather 2: h2 = relu(agg*nd + b), fp32 out ----------------
__global__ __launch_bounds__(256) void k_gather2(const _Float16* __restrict__ P,
                                                 const int* __restrict__ row_end,
                                                 const int* __restrict__ csr,
                                                 const float* __restrict__ bias,
                                                 float2* __restrict__ outH, int N) {
  int wid = (blockIdx.x * 256 + threadIdx.x) >> 6;
  if (wid >= N) return;
  int lane = threadIdx.x & 63;
  int end = row_end[wid];
  int start = (wid == 0) ? 0 : row_end[wid - 1];
  float ax = 0.f, ay = 0.f;
  const half2v* P2 = (const half2v*)P;
  for (int base = start; base < end; base += 64) {
    int nb = min(64, end - base);
    int idx = (base + lane < end) ? csr[base + lane] : 0;
    int j = 0;
    for (; j + 4 <= nb; j += 4) {
      int s0 = __shfl(idx, j), s1 = __shfl(idx, j + 1);
      int s2 = __shfl(idx, j + 2), s3 = __shfl(idx, j + 3);
      half2v v0 = P2[(size_t)s0 * 64 + lane];
      half2v v1 = P2[(size_t)s1 * 64 + lane];
      half2v v2 = P2[(size_t)s2 * 64 + lane];
      half2v v3 = P2[(size_t)s3 * 64 + lane];
      ax += (float)v0.x + (float)v1.x + (float)v2.x + (float)v3.x;
      ay += (float)v0.y + (float)v1.y + (float)v2.y + (float)v3.y;
    }
    for (; j < nb; ++j) {
      int s = __shfl(idx, j);
      half2v v = P2[(size_t)s * 64 + lane];
      ax += (float)v.x; ay += (float)v.y;
    }
  }
  float nd = rsqrtf(fmaxf((float)(end - start), 1.0f));
  float2 b = ((const float2*)bias)[lane];
  float2 o;
  o.x = fmaxf(ax * nd + b.x, 0.f);
  o.y = fmaxf(ay * nd + b.y, 0.f);
  outH[(size_t)wid * 64 + lane] = o;
}

// ---------------- per-graph node counts (LDS histogram, int) ----------------
__global__ __launch_bounds__(256) void k_counts(const int* __restrict__ gid,
                                                int* __restrict__ counts, int N) {
  __shared__ int h[64];
  if (threadIdx.x < 64) h[threadIdx.x] = 0;
  __syncthreads();
  int i = blockIdx.x * 256 + threadIdx.x;
  if (i < N) atomicAdd(&h[gid[i]], 1);
  __syncthreads();
  if (threadIdx.x < 64 && h[threadIdx.x] > 0)
    atomicAdd(&counts[threadIdx.x], h[threadIdx.x]);
}

// ---------------- graph_ptr ----------------
__global__ __launch_bounds__(64) void k_gptr(const int* __restrict__ counts,
                                             int* __restrict__ gptr) {
  if (threadIdx.x == 0) {
    int run = 0;
    for (int g = 0; g < 64; ++g) {
      gptr[g] = run;
      run += counts[g];
    }
    gptr[64] = run;
  }
}

// ---------------- segment-sum pooling over sorted graph_id ----------------
__global__ __launch_bounds__(256) void k_pool(const float* __restrict__ H,
                                              const int* __restrict__ gptr,
                                              float* __restrict__ pool) {
  int g = blockIdx.x >> 3, chunk = blockIdx.x & 7;
  int col = threadIdx.x & 127, rpar = threadIdx.x >> 7;
  int s = gptr[g], e = gptr[g + 1];
  float acc = 0.0f;
  for (int r = s + chunk * 2 + rpar; r < e; r += 16)
    acc += H[(size_t)r * D + col];
  __shared__ float red[256];
  red[threadIdx.x] = acc;
  __syncthreads();
  if (rpar == 0) atomicAdd(&pool[g * D + col], acc + red[threadIdx.x + 128]);
}

// ---------------- readout MLP ----------------
__global__ __launch_bounds__(128) void k_readout(const float* __restrict__ pool,
                                                 const int* __restrict__ counts,
                                                 const float* __restrict__ Wr1,
                                                 const float* __restrict__ br1,
                                                 const float* __restrict__ Wr2,
                                                 const float* __restrict__ br2,
                                                 float* __restrict__ out) {
  int g = blockIdx.x;
  int j = threadIdx.x;
  __shared__ float hg[D];
  __shared__ float t1[D];
  float cnt = fmaxf((float)counts[g], 1.0f);
  hg[j] = pool[(size_t)g * D + j] / cnt;
  __syncthreads();
  float a = br1[j];
  for (int k = 0; k < D; ++k) a += hg[k] * Wr1[(size_t)k * D + j];
  t1[j] = fmaxf(a, 0.0f);
  __syncthreads();
  float b = br2[j];
  for (int k = 0; k < D; ++k) b += t1[k] * Wr2[(size_t)k * D + j];
  out[(size_t)g * D + j] = b;
}

extern "C" void kernel_launch(void* const* d_in, const int* in_sizes, int n_in,
                              void* d_out, int out_size, void* d_ws, size_t ws_size,
                              hipStream_t stream) {
  const float* x   = (const float*)d_in[0];
  const int* edge  = (const int*)d_in[1];
  const int* gid   = (const int*)d_in[2];
  const float* W1  = (const float*)d_in[4];
  const float* b1  = (const float*)d_in[5];
  const float* W2  = (const float*)d_in[6];
  const float* b2  = (const float*)d_in[7];
  const float* Wr1 = (const float*)d_in[8];
  const float* br1 = (const float*)d_in[9];
  const float* Wr2 = (const float*)d_in[10];
  const float* br2 = (const float*)d_in[11];

  const int N = in_sizes[0] / D;   // 100000
  const int E = in_sizes[1] / 2;   // 1600000
  const int* src = edge;
  const int* dst = edge + E;
  const int nbkt = (N + BSZ - 1) >> BSH;  // 196

  // workspace layout (regions kept float-sized from R4; halves use half of each)
  float* bufA     = (float*)d_ws;                    // P (half N*128) lives here
  float* bufB     = bufA + (size_t)N * D;            // h1' (half N*128) lives here
  int* row_end    = (int*)(bufB + (size_t)N * D);    // N
  int* csr        = row_end + N;                     // E
  float* norm_src = (float*)(csr + E);               // N
  float* pool     = norm_src + N;                    // 64*128
  int* counts     = (int*)(pool + 64 * D);           // 64
  int* gptr       = counts + 64;                     // 65
  int* cnt_d      = gptr + 65;                       // 256
  int* cnt_s      = cnt_d + 256;                     // 256
  int* ptr_d      = cnt_s + 256;                     // 257
  int* ptr_s      = ptr_d + 257;                     // 257
  int* cur_d      = ptr_s + 257;                     // 256
  int* cur_s      = cur_d + 256;                     // 256
  _Float16* Wt1   = (_Float16*)(cur_s + 256);        // 128*128 halves
  _Float16* Wt2   = Wt1 + 128 * 128;                 // 128*128 halves
  // temporary packed edge arrays alias bufA (consumed before gemm1 writes it)
  int* packed_d   = (int*)bufA;                      // E
  int* packed_s   = packed_d + E;                    // E
  size_t need = ((size_t)2 * N * D + 2 * N + E + 64 * D + 64 + 65 + 1538 + 8192)
                * sizeof(float);
  if (ws_size < need) return;

  float* out_g = (float*)d_out;      // 64*128
  float* h_out = out_g + 64 * D;     // N*128

  _Float16* P   = (_Float16*)bufA;
  _Float16* h1p = (_Float16*)bufB;

  hipMemsetAsync(cnt_d, 0, 512 * sizeof(int), stream);              // cnt_d + cnt_s
  hipMemsetAsync(pool, 0, (64 * D + 64) * sizeof(float), stream);   // pool + counts

  // weight prep (independent)
  k_prep<<<128, 256, 0, stream>>>(W1, W2, Wt1, Wt2);

  // graph structure via two-level counting sort
  k_coarse<<<256, 256, 0, stream>>>(src, dst, cnt_d, cnt_s, E, nbkt);
  k_cscan<<<1, 256, 0, stream>>>(cnt_d, cnt_s, ptr_d, cur_d, ptr_s, cur_s, nbkt, E);
  k_cscatter<<<256, 256, 0, stream>>>(src, dst, cur_d, cur_s, packed_d, packed_s, E, nbkt);
  k_fine_dst<<<nbkt, 256, 0, stream>>>(packed_d, ptr_d, row_end, csr, N);
  k_fine_src<<<nbkt, 256, 0, stream>>>(packed_s, ptr_s, norm_src, N);

  const int gemm_grid = (N + 63) / 64;

  // layer 1
  k_gemm1<<<gemm_grid, 256, 0, stream>>>(x, Wt1, norm_src, P, N);
  k_gather1<<<(N * 64 + 255) / 256, 256, 0, stream>>>(
      P, row_end, csr, b1, norm_src, h1p, N);

  // layer 2
  k_gemm2<<<gemm_grid, 256, 0, stream>>>(h1p, Wt2, P, N);
  k_gather2<<<(N * 64 + 255) / 256, 256, 0, stream>>>(
      P, row_end, csr, b2, (float2*)h_out, N);

  // pooling + readout
  k_counts<<<(N + 255) / 256, 256, 0, stream>>>(gid, counts, N);
  k_gptr<<<1, 64, 0, stream>>>(counts, gptr);
  k_pool<<<64 * 8, 256, 0, stream>>>(h_out, gptr, pool);
  k_readout<<<64, 128, 0, stream>>>(pool, counts, Wr1, br1, Wr2, br2, out_g);
}

// Round 6
// 437.602 us; speedup vs baseline: 14.3214x; 1.0106x over previous
//
#include <hip/hip_runtime.h>
#include <math.h>

// GCN: h1 = relu(norm_dst * A * (norm_src * x) @ W1 + b1)
//      h2 = relu(norm_dst * A * (norm_src * h1) @ W2 + b2)
//      hg = mean_per_graph(h2); out = relu(hg@Wr1+br1)@Wr2+br2
// d_out = [out (64*128) | h2 (N*128)]
//
// R2: scatter-atomic SpMM -> CSR-by-dst + register gather (fused norm/bias/relu).
// R3: single-block scan -> 3-phase hierarchical scan.
// R4: degree/bucket random atomics -> two-level counting sort (LDS histograms).
// R5: fp16 pipeline: mfma_f32_16x16x32_f16 GEMMs, fp16 P/h1' (row 512B->256B).
// R6: gather re-mapped to (4 edges x 16 col-groups) per wave: one dwordx4 load
//     covers 4 edges, no shuffle broadcast, v_dot2_f32_f16 accumulation
//     (halves VALU math); k_counts replaced by binary-search gptr over the
//     sorted graph_id.
// Assumes N <= 131072 (src fits 17 bits in packing).

#define D 128
#define BSH 9
#define BSZ 512

typedef _Float16 half8 __attribute__((ext_vector_type(8)));
typedef _Float16 half4v __attribute__((ext_vector_type(4)));
typedef _Float16 half2v __attribute__((ext_vector_type(2)));
typedef float f32x4 __attribute__((ext_vector_type(4)));

union H8 { half8 v; half2v h[4]; };

// ---------------- coarse histogram (dst>>9 and src>>9) ----------------
__global__ __launch_bounds__(256) void k_coarse(const int* __restrict__ src,
                                                const int* __restrict__ dst,
                                                int* __restrict__ cnt_d,
                                                int* __restrict__ cnt_s,
                                                int E, int nbkt) {
  __shared__ int hd[256], hs[256];
  int t = threadIdx.x;
  hd[t] = 0; hs[t] = 0;
  __syncthreads();
  int chunk = (E + gridDim.x - 1) / gridDim.x;
  int lo = blockIdx.x * chunk, hi = min(lo + chunk, E);
  for (int e = lo + t; e < hi; e += 256) {
    atomicAdd(&hd[dst[e] >> BSH], 1);
    atomicAdd(&hs[src[e] >> BSH], 1);
  }
  __syncthreads();
  if (t < nbkt) {
    if (hd[t]) atomicAdd(&cnt_d[t], hd[t]);
    if (hs[t]) atomicAdd(&cnt_s[t], hs[t]);
  }
}

// ---------------- scan coarse counts -> bucket ptrs + cursors ----------------
__global__ __launch_bounds__(256) void k_cscan(const int* __restrict__ cnt_d,
                                               const int* __restrict__ cnt_s,
                                               int* __restrict__ ptr_d,
                                               int* __restrict__ cur_d,
                                               int* __restrict__ ptr_s,
                                               int* __restrict__ cur_s,
                                               int nbkt, int E) {
  __shared__ int sh[256];
  int t = threadIdx.x;
  int v = (t < nbkt) ? cnt_d[t] : 0;
  sh[t] = v;
  __syncthreads();
  for (int off = 1; off < 256; off <<= 1) {
    int a = (t >= off) ? sh[t - off] : 0;
    __syncthreads();
    sh[t] += a;
    __syncthreads();
  }
  if (t < nbkt) { int ex = sh[t] - v; ptr_d[t] = ex; cur_d[t] = ex; }
  if (t == 0) ptr_d[nbkt] = E;
  __syncthreads();
  v = (t < nbkt) ? cnt_s[t] : 0;
  sh[t] = v;
  __syncthreads();
  for (int off = 1; off < 256; off <<= 1) {
    int a = (t >= off) ? sh[t - off] : 0;
    __syncthreads();
    sh[t] += a;
    __syncthreads();
  }
  if (t < nbkt) { int ex = sh[t] - v; ptr_s[t] = ex; cur_s[t] = ex; }
  if (t == 0) ptr_s[nbkt] = E;
}

// ---------------- coarse scatter: packed edges into buckets ----------------
__global__ __launch_bounds__(256) void k_cscatter(const int* __restrict__ src,
                                                  const int* __restrict__ dst,
                                                  int* __restrict__ cur_d,
                                                  int* __restrict__ cur_s,
                                                  int* __restrict__ packed_d,
                                                  int* __restrict__ packed_s,
                                                  int E, int nbkt) {
  __shared__ int hd[256], hs[256], bd[256], bs2[256];
  int t = threadIdx.x;
  hd[t] = 0; hs[t] = 0;
  __syncthreads();
  int chunk = (E + gridDim.x - 1) / gridDim.x;
  int lo = blockIdx.x * chunk, hi = min(lo + chunk, E);
  for (int e = lo + t; e < hi; e += 256) {
    atomicAdd(&hd[dst[e] >> BSH], 1);
    atomicAdd(&hs[src[e] >> BSH], 1);
  }
  __syncthreads();
  if (t < nbkt) {
    bd[t] = hd[t] ? atomicAdd(&cur_d[t], hd[t]) : 0;
    bs2[t] = hs[t] ? atomicAdd(&cur_s[t], hs[t]) : 0;
  }
  __syncthreads();
  hd[t] = 0; hs[t] = 0;
  __syncthreads();
  for (int e = lo + t; e < hi; e += 256) {
    int s = src[e], d = dst[e];
    int b1 = d >> BSH;
    int r1 = atomicAdd(&hd[b1], 1);
    packed_d[bd[b1] + r1] = ((d & (BSZ - 1)) << 17) | s;
    int b2 = s >> BSH;
    int r2 = atomicAdd(&hs[b2], 1);
    packed_s[bs2[b2] + r2] = s & (BSZ - 1);
  }
}

// ---------------- fine pass (dst): row_end + CSR ----------------
__global__ __launch_bounds__(256) void k_fine_dst(const int* __restrict__ packed_d,
                                                  const int* __restrict__ ptr_d,
                                                  int* __restrict__ row_end,
                                                  int* __restrict__ csr, int N) {
  __shared__ int hist[512], excl[512], ps[256];
  int b = blockIdx.x, t = threadIdx.x;
  int lo = ptr_d[b], hi = ptr_d[b + 1];
  hist[t] = 0; hist[t + 256] = 0;
  __syncthreads();
  for (int e = lo + t; e < hi; e += 256)
    atomicAdd(&hist[packed_d[e] >> 17], 1);
  __syncthreads();
  int a0 = hist[2 * t], a1 = hist[2 * t + 1];
  ps[t] = a0 + a1;
  __syncthreads();
  for (int off = 1; off < 256; off <<= 1) {
    int a = (t >= off) ? ps[t - off] : 0;
    __syncthreads();
    ps[t] += a;
    __syncthreads();
  }
  int exc = ps[t] - (a0 + a1);
  excl[2 * t] = exc;
  excl[2 * t + 1] = exc + a0;
  int nbase = b << BSH;
  if (nbase + 2 * t < N)     row_end[nbase + 2 * t]     = lo + exc + a0;
  if (nbase + 2 * t + 1 < N) row_end[nbase + 2 * t + 1] = lo + exc + a0 + a1;
  __syncthreads();
  hist[t] = 0; hist[t + 256] = 0;
  __syncthreads();
  for (int e = lo + t; e < hi; e += 256) {
    int p = packed_d[e];
    int dlow = p >> 17, s = p & 0x1FFFF;
    int r = atomicAdd(&hist[dlow], 1);
    csr[lo + excl[dlow] + r] = s;
  }
}

// ---------------- fine pass (src): norm_src = rsqrt(max(deg_out,1)) ----------
__global__ __launch_bounds__(256) void k_fine_src(const int* __restrict__ packed_s,
                                                  const int* __restrict__ ptr_s,
                                                  float* __restrict__ norm_src, int N) {
  __shared__ int hist[512];
  int b = blockIdx.x, t = threadIdx.x;
  int lo = ptr_s[b], hi = ptr_s[b + 1];
  hist[t] = 0; hist[t + 256] = 0;
  __syncthreads();
  for (int e = lo + t; e < hi; e += 256)
    atomicAdd(&hist[packed_s[e]], 1);
  __syncthreads();
  int nbase = b << BSH;
  for (int i = t; i < BSZ; i += 256)
    if (nbase + i < N)
      norm_src[nbase + i] = rsqrtf(fmaxf((float)hist[i], 1.0f));
}

// ---------------- prep: Wt[n][k] = (half)W[k][n] for W1,W2 ----------------
__global__ __launch_bounds__(256) void k_prep(const float* __restrict__ W1,
                                              const float* __restrict__ W2,
                                              _Float16* __restrict__ Wt1,
                                              _Float16* __restrict__ Wt2) {
  int idx = blockIdx.x * 256 + threadIdx.x;   // grid 128 -> 32768 threads
  int m = idx >> 14;
  int i = idx & 16383;
  int k = i >> 7, n = i & 127;
  const float* W = m ? W2 : W1;
  _Float16* Wt = m ? Wt2 : Wt1;
  Wt[n * 128 + k] = (_Float16)W[i];  // i == k*128+n
}

// ---------------- MFMA GEMM (fp32 input): C(half) = (scale*A)@W ----------------
__global__ __launch_bounds__(256) void k_gemm1(const float* __restrict__ A,
                                               const _Float16* __restrict__ Wt,
                                               const float* __restrict__ scale,
                                               _Float16* __restrict__ C, int N) {
  __shared__ _Float16 As[64][136];
  __shared__ _Float16 Cs[64][128];
  const int r0 = blockIdx.x * 64;
  const int t = threadIdx.x;
  for (int i = t; i < 64 * 32; i += 256) {
    int r = i >> 5, c4 = i & 31;
    float4 v = {0.f, 0.f, 0.f, 0.f};
    if (r0 + r < N) {
      v = ((const float4*)A)[(size_t)(r0 + r) * 32 + c4];
      float s = scale[r0 + r];
      v.x *= s; v.y *= s; v.z *= s; v.w *= s;
    }
    half4v h = {(_Float16)v.x, (_Float16)v.y, (_Float16)v.z, (_Float16)v.w};
    *(half4v*)&As[r][c4 * 4] = h;
  }
  __syncthreads();
  const int w = t >> 6, l = t & 63;
  const int c = l & 15, quad = l >> 4;
  f32x4 acc[8];
#pragma unroll
  for (int nt = 0; nt < 8; ++nt) acc[nt] = (f32x4){0.f, 0.f, 0.f, 0.f};
#pragma unroll
  for (int kc = 0; kc < 4; ++kc) {
    half8 a = *(const half8*)&As[w * 16 + c][kc * 32 + quad * 8];
#pragma unroll
    for (int nt = 0; nt < 8; ++nt) {
      half8 b = *(const half8*)&Wt[(size_t)(nt * 16 + c) * 128 + kc * 32 + quad * 8];
      acc[nt] = __builtin_amdgcn_mfma_f32_16x16x32_f16(a, b, acc[nt], 0, 0, 0);
    }
  }
#pragma unroll
  for (int nt = 0; nt < 8; ++nt)
#pragma unroll
    for (int r = 0; r < 4; ++r)
      Cs[w * 16 + quad * 4 + r][nt * 16 + c] = (_Float16)acc[nt][r];
  __syncthreads();
  for (int i = t; i < 64 * 16; i += 256) {
    int r = i >> 4, c8 = i & 15;
    if (r0 + r < N)
      ((half8*)C)[(size_t)(r0 + r) * 16 + c8] = *(half8*)&Cs[r][c8 * 8];
  }
}

// ---------------- MFMA GEMM (fp16 pre-scaled input): C(half) = A@W -----------
__global__ __launch_bounds__(256) void k_gemm2(const _Float16* __restrict__ A,
                                               const _Float16* __restrict__ Wt,
                                               _Float16* __restrict__ C, int N) {
  __shared__ _Float16 As[64][136];
  __shared__ _Float16 Cs[64][128];
  const int r0 = blockIdx.x * 64;
  const int t = threadIdx.x;
  for (int i = t; i < 64 * 16; i += 256) {
    int r = i >> 4, c8 = i & 15;
    half8 v = {0, 0, 0, 0, 0, 0, 0, 0};
    if (r0 + r < N) v = ((const half8*)A)[(size_t)(r0 + r) * 16 + c8];
    *(half8*)&As[r][c8 * 8] = v;
  }
  __syncthreads();
  const int w = t >> 6, l = t & 63;
  const int c = l & 15, quad = l >> 4;
  f32x4 acc[8];
#pragma unroll
  for (int nt = 0; nt < 8; ++nt) acc[nt] = (f32x4){0.f, 0.f, 0.f, 0.f};
#pragma unroll
  for (int kc = 0; kc < 4; ++kc) {
    half8 a = *(const half8*)&As[w * 16 + c][kc * 32 + quad * 8];
#pragma unroll
    for (int nt = 0; nt < 8; ++nt) {
      half8 b = *(const half8*)&Wt[(size_t)(nt * 16 + c) * 128 + kc * 32 + quad * 8];
      acc[nt] = __builtin_amdgcn_mfma_f32_16x16x32_f16(a, b, acc[nt], 0, 0, 0);
    }
  }
#pragma unroll
  for (int nt = 0; nt < 8; ++nt)
#pragma unroll
    for (int r = 0; r < 4; ++r)
      Cs[w * 16 + quad * 4 + r][nt * 16 + c] = (_Float16)acc[nt][r];
  __syncthreads();
  for (int i = t; i < 64 * 16; i += 256) {
    int r = i >> 4, c8 = i & 15;
    if (r0 + r < N)
      ((half8*)C)[(size_t)(r0 + r) * 16 + c8] = *(half8*)&Cs[r][c8 * 8];
  }
}

// ---------------- gather core: 4 edges x 16 col-groups per wave ----------------
// lane = eg*16 + cg is WRONG mapping; we use cg = lane&15, eg = lane>>4 so the
// 16-byte loads of the 16 cg lanes of one eg are contiguous (one 256B row).
// acc[j] accumulates column cg*8+j in fp32 via v_dot2_f32_f16.
__device__ __forceinline__ void gather_core(const half8* __restrict__ P8,
                                            const int* __restrict__ csr,
                                            int start, int end, int cg, int eg,
                                            float* acc) {
  const half2v c10 = {(_Float16)1.0f, (_Float16)0.0f};
  const half2v c01 = {(_Float16)0.0f, (_Float16)1.0f};
  int base = start;
  for (; base + 8 <= end; base += 8) {
    int i0 = csr[base + eg];
    int i1 = csr[base + 4 + eg];
    H8 u0, u1;
    u0.v = P8[(size_t)i0 * 16 + cg];
    u1.v = P8[(size_t)i1 * 16 + cg];
#pragma unroll
    for (int k = 0; k < 4; ++k) {
      acc[2 * k]     = __builtin_amdgcn_fdot2(u0.h[k], c10, acc[2 * k], false);
      acc[2 * k + 1] = __builtin_amdgcn_fdot2(u0.h[k], c01, acc[2 * k + 1], false);
      acc[2 * k]     = __builtin_amdgcn_fdot2(u1.h[k], c10, acc[2 * k], false);
      acc[2 * k + 1] = __builtin_amdgcn_fdot2(u1.h[k], c01, acc[2 * k + 1], false);
    }
  }
  for (; base < end; base += 4) {
    int e = base + eg;
    if (e < end) {
      H8 u;
      u.v = P8[(size_t)csr[e] * 16 + cg];
#pragma unroll
      for (int k = 0; k < 4; ++k) {
        acc[2 * k]     = __builtin_amdgcn_fdot2(u.h[k], c10, acc[2 * k], false);
        acc[2 * k + 1] = __builtin_amdgcn_fdot2(u.h[k], c01, acc[2 * k + 1], false);
      }
    }
  }
  // reduce across the 4 edge-groups (lanes differing in bits 4,5)
#pragma unroll
  for (int j = 0; j < 8; ++j) {
    acc[j] += __shfl_xor(acc[j], 16);
    acc[j] += __shfl_xor(acc[j], 32);
  }
}

// gather 1: h1' = norm_src * relu(agg*nd + b), fp16 out
__global__ __launch_bounds__(256) void k_gather1(const half8* __restrict__ P8,
                                                 const int* __restrict__ row_end,
                                                 const int* __restrict__ csr,
                                                 const float* __restrict__ bias,
                                                 const float* __restrict__ norm_src,
                                                 half2v* __restrict__ outH, int N) {
  int wid = (blockIdx.x * 256 + threadIdx.x) >> 6;
  if (wid >= N) return;
  int lane = threadIdx.x & 63;
  int cg = lane & 15, eg = lane >> 4;
  int end = row_end[wid];
  int start = (wid == 0) ? 0 : row_end[wid - 1];
  float acc[8] = {0.f, 0.f, 0.f, 0.f, 0.f, 0.f, 0.f, 0.f};
  gather_core(P8, csr, start, end, cg, eg, acc);
  float nd = rsqrtf(fmaxf((float)(end - start), 1.0f));
  float ns = norm_src[wid];
  float2 b = ((const float2*)bias)[cg * 4 + eg];
  half2v o = {(_Float16)(fmaxf(acc[eg * 2] * nd + b.x, 0.f) * ns),
              (_Float16)(fmaxf(acc[eg * 2 + 1] * nd + b.y, 0.f) * ns)};
  outH[(size_t)wid * 64 + cg * 4 + eg] = o;
}

// gather 2: h2 = relu(agg*nd + b), fp32 out
__global__ __launch_bounds__(256) void k_gather2(const half8* __restrict__ P8,
                                                 const int* __restrict__ row_end,
                                                 const int* __restrict__ csr,
                                                 const float* __restrict__ bias,
                                                 float2* __restrict__ outH, int N) {
  int wid = (blockIdx.x * 256 + threadIdx.x) >> 6;
  if (wid >= N) return;
  int lane = threadIdx.x & 63;
  int cg = lane & 15, eg = lane >> 4;
  int end = row_end[wid];
  int start = (wid == 0) ? 0 : row_end[wid - 1];
  float acc[8] = {0.f, 0.f, 0.f, 0.f, 0.f, 0.f, 0.f, 0.f};
  gather_core(P8, csr, start, end, cg, eg, acc);
  float nd = rsqrtf(fmaxf((float)(end - start), 1.0f));
  float2 b = ((const float2*)bias)[cg * 4 + eg];
  float2 o;
  o.x = fmaxf(acc[eg * 2] * nd + b.x, 0.f);
  o.y = fmaxf(acc[eg * 2 + 1] * nd + b.y, 0.f);
  outH[(size_t)wid * 64 + cg * 4 + eg] = o;
}

// ---------------- gptr[g] = lower_bound(gid, g) over sorted gid ----------------
__global__ __launch_bounds__(128) void k_gptr(const int* __restrict__ gid,
                                              int* __restrict__ gptr, int N) {
  int g = threadIdx.x;
  if (g > 64) return;
  int lo = 0, hi = N;
  while (lo < hi) {
    int m = (lo + hi) >> 1;
    if (gid[m] < g) lo = m + 1; else hi = m;
  }
  gptr[g] = lo;
}

// ---------------- segment-sum pooling over sorted graph_id ----------------
__global__ __launch_bounds__(256) void k_pool(const float* __restrict__ H,
                                              const int* __restrict__ gptr,
                                              float* __restrict__ pool) {
  int g = blockIdx.x >> 3, chunk = blockIdx.x & 7;
  int col = threadIdx.x & 127, rpar = threadIdx.x >> 7;
  int s = gptr[g], e = gptr[g + 1];
  float acc = 0.0f;
  for (int r = s + chunk * 2 + rpar; r < e; r += 16)
    acc += H[(size_t)r * D + col];
  __shared__ float red[256];
  red[threadIdx.x] = acc;
  __syncthreads();
  if (rpar == 0) atomicAdd(&pool[g * D + col], acc + red[threadIdx.x + 128]);
}

// ---------------- readout MLP ----------------
__global__ __launch_bounds__(128) void k_readout(const float* __restrict__ pool,
                                                 const int* __restrict__ gptr,
                                                 const float* __restrict__ Wr1,
                                                 const float* __restrict__ br1,
                                                 const float* __restrict__ Wr2,
                                                 const float* __restrict__ br2,
                                                 float* __restrict__ out) {
  int g = blockIdx.x;
  int j = threadIdx.x;
  __shared__ float hg[D];
  __shared__ float t1[D];
  float cnt = fmaxf((float)(gptr[g + 1] - gptr[g]), 1.0f);
  hg[j] = pool[(size_t)g * D + j] / cnt;
  __syncthreads();
  float a = br1[j];
  for (int k = 0; k < D; ++k) a += hg[k] * Wr1[(size_t)k * D + j];
  t1[j] = fmaxf(a, 0.0f);
  __syncthreads();
  float b = br2[j];
  for (int k = 0; k < D; ++k) b += t1[k] * Wr2[(size_t)k * D + j];
  out[(size_t)g * D + j] = b;
}

extern "C" void kernel_launch(void* const* d_in, const int* in_sizes, int n_in,
                              void* d_out, int out_size, void* d_ws, size_t ws_size,
                              hipStream_t stream) {
  const float* x   = (const float*)d_in[0];
  const int* edge  = (const int*)d_in[1];
  const int* gid   = (const int*)d_in[2];
  const float* W1  = (const float*)d_in[4];
  const float* b1  = (const float*)d_in[5];
  const float* W2  = (const float*)d_in[6];
  const float* b2  = (const float*)d_in[7];
  const float* Wr1 = (const float*)d_in[8];
  const float* br1 = (const float*)d_in[9];
  const float* Wr2 = (const float*)d_in[10];
  const float* br2 = (const float*)d_in[11];

  const int N = in_sizes[0] / D;   // 100000
  const int E = in_sizes[1] / 2;   // 1600000
  const int* src = edge;
  const int* dst = edge + E;
  const int nbkt = (N + BSZ - 1) >> BSH;  // 196

  // workspace layout
  float* bufA     = (float*)d_ws;                    // P (half N*128) lives here
  float* bufB     = bufA + (size_t)N * D;            // h1' (half N*128) lives here
  int* row_end    = (int*)(bufB + (size_t)N * D);    // N
  int* csr        = row_end + N;                     // E
  float* norm_src = (float*)(csr + E);               // N
  float* pool     = norm_src + N;                    // 64*128
  int* gptr       = (int*)(pool + 64 * D);           // 65
  int* cnt_d      = gptr + 65;                       // 256
  int* cnt_s      = cnt_d + 256;                     // 256
  int* ptr_d      = cnt_s + 256;                     // 257
  int* ptr_s      = ptr_d + 257;                     // 257
  int* cur_d      = ptr_s + 257;                     // 256
  int* cur_s      = cur_d + 256;                     // 256
  _Float16* Wt1   = (_Float16*)(cur_s + 256);        // 128*128 halves
  _Float16* Wt2   = Wt1 + 128 * 128;                 // 128*128 halves
  // temporary packed edge arrays alias bufA (consumed before gemm1 writes it)
  int* packed_d   = (int*)bufA;                      // E
  int* packed_s   = packed_d + E;                    // E
  size_t need = ((size_t)2 * N * D + 2 * N + E + 64 * D + 65 + 1538 + 8192)
                * sizeof(float);
  if (ws_size < need) return;

  float* out_g = (float*)d_out;      // 64*128
  float* h_out = out_g + 64 * D;     // N*128

  _Float16* P   = (_Float16*)bufA;
  _Float16* h1p = (_Float16*)bufB;

  hipMemsetAsync(cnt_d, 0, 512 * sizeof(int), stream);              // cnt_d + cnt_s
  hipMemsetAsync(pool, 0, 64 * D * sizeof(float), stream);

  // weight prep + graph pooling ptrs (independent)
  k_prep<<<128, 256, 0, stream>>>(W1, W2, Wt1, Wt2);
  k_gptr<<<1, 128, 0, stream>>>(gid, gptr, N);

  // graph structure via two-level counting sort
  k_coarse<<<256, 256, 0, stream>>>(src, dst, cnt_d, cnt_s, E, nbkt);
  k_cscan<<<1, 256, 0, stream>>>(cnt_d, cnt_s, ptr_d, cur_d, ptr_s, cur_s, nbkt, E);
  k_cscatter<<<256, 256, 0, stream>>>(src, dst, cur_d, cur_s, packed_d, packed_s, E, nbkt);
  k_fine_dst<<<nbkt, 256, 0, stream>>>(packed_d, ptr_d, row_end, csr, N);
  k_fine_src<<<nbkt, 256, 0, stream>>>(packed_s, ptr_s, norm_src, N);

  const int gemm_grid = (N + 63) / 64;

  // layer 1
  k_gemm1<<<gemm_grid, 256, 0, stream>>>(x, Wt1, norm_src, P, N);
  k_gather1<<<(N * 64 + 255) / 256, 256, 0, stream>>>(
      (const half8*)P, row_end, csr, b1, norm_src, (half2v*)h1p, N);

  // layer 2
  k_gemm2<<<gemm_grid, 256, 0, stream>>>(h1p, Wt2, P, N);
  k_gather2<<<(N * 64 + 255) / 256, 256, 0, stream>>>(
      (const half8*)P, row_end, csr, b2, (float2*)h_out, N);

  // pooling + readout
  k_pool<<<64 * 8, 256, 0, stream>>>(h_out, gptr, pool);
  k_readout<<<64, 128, 0, stream>>>(pool, gptr, Wr1, br1, Wr2, br2, out_g);
}

// Round 7
// 423.761 us; speedup vs baseline: 14.7891x; 1.0327x over previous
//
#include <hip/hip_runtime.h>
#include <math.h>

// GCN: h1 = relu(norm_dst * A * (norm_src * x) @ W1 + b1)
//      h2 = relu(norm_dst * A * (norm_src * h1) @ W2 + b2)
//      hg = mean_per_graph(h2); out = relu(hg@Wr1+br1)@Wr2+br2
// d_out = [out (64*128) | h2 (N*128)]
//
// R2: scatter-atomic SpMM -> CSR-by-dst + register gather (fused norm/bias/relu).
// R3: single-block scan -> 3-phase hierarchical scan.
// R4: degree/bucket random atomics -> two-level counting sort (LDS histograms).
// R5: fp16 pipeline: mfma_f32_16x16x32_f16 GEMMs, fp16 P/h1' (row 512B->256B).
// R6: gather (4 edges x 16 col-groups)/wave, fdot2 accumulation, bsearch gptr.
// R7: gather MLP: hoist csr via coalesced load + shfl distribute, 4 rows in
//     flight per lane (16 edges/iter); k_coarse exports per-block bucket bases
//     so k_cscatter skips its histogram pass; gptr fused into cscan.
// Assumes N <= 131072 (src fits 17 bits in packing).

#define D 128
#define BSH 9
#define BSZ 512

typedef _Float16 half8 __attribute__((ext_vector_type(8)));
typedef _Float16 half4v __attribute__((ext_vector_type(4)));
typedef _Float16 half2v __attribute__((ext_vector_type(2)));
typedef float f32x4 __attribute__((ext_vector_type(4)));

union H8 { half8 v; half2v h[4]; };

// ---------------- coarse histogram + per-block bucket bases ----------------
__global__ __launch_bounds__(256) void k_coarse(const int* __restrict__ src,
                                                const int* __restrict__ dst,
                                                int* __restrict__ cnt_d,
                                                int* __restrict__ cnt_s,
                                                int* __restrict__ blkbase_d,
                                                int* __restrict__ blkbase_s,
                                                int E, int nbkt) {
  __shared__ int hd[256], hs[256];
  int t = threadIdx.x;
  hd[t] = 0; hs[t] = 0;
  __syncthreads();
  int chunk = (E + gridDim.x - 1) / gridDim.x;
  int lo = blockIdx.x * chunk, hi = min(lo + chunk, E);
  for (int e = lo + t; e < hi; e += 256) {
    atomicAdd(&hd[dst[e] >> BSH], 1);
    atomicAdd(&hs[src[e] >> BSH], 1);
  }
  __syncthreads();
  if (t < nbkt) {
    int c = hd[t];
    blkbase_d[blockIdx.x * 256 + t] = c ? atomicAdd(&cnt_d[t], c) : 0;
    c = hs[t];
    blkbase_s[blockIdx.x * 256 + t] = c ? atomicAdd(&cnt_s[t], c) : 0;
  }
}

// ---------------- scan coarse counts -> ptrs; fused gptr bsearch ----------------
__global__ __launch_bounds__(256) void k_cscan(const int* __restrict__ cnt_d,
                                               const int* __restrict__ cnt_s,
                                               int* __restrict__ ptr_d,
                                               int* __restrict__ ptr_s,
                                               const int* __restrict__ gid,
                                               int* __restrict__ gptr,
                                               int nbkt, int E, int N) {
  __shared__ int sh[256];
  int t = threadIdx.x;
  int v = (t < nbkt) ? cnt_d[t] : 0;
  sh[t] = v;
  __syncthreads();
  for (int off = 1; off < 256; off <<= 1) {
    int a = (t >= off) ? sh[t - off] : 0;
    __syncthreads();
    sh[t] += a;
    __syncthreads();
  }
  if (t < nbkt) ptr_d[t] = sh[t] - v;
  if (t == 0) ptr_d[nbkt] = E;
  __syncthreads();
  v = (t < nbkt) ? cnt_s[t] : 0;
  sh[t] = v;
  __syncthreads();
  for (int off = 1; off < 256; off <<= 1) {
    int a = (t >= off) ? sh[t - off] : 0;
    __syncthreads();
    sh[t] += a;
    __syncthreads();
  }
  if (t < nbkt) ptr_s[t] = sh[t] - v;
  if (t == 0) ptr_s[nbkt] = E;
  // gptr[g] = lower_bound(gid, g), g in [0,64]
  if (t <= 64) {
    int lo = 0, hi = N;
    while (lo < hi) {
      int m = (lo + hi) >> 1;
      if (gid[m] < t) lo = m + 1; else hi = m;
    }
    gptr[t] = lo;
  }
}

// ---------------- coarse scatter (single pass; bases precomputed) ----------------
__global__ __launch_bounds__(256) void k_cscatter(const int* __restrict__ src,
                                                  const int* __restrict__ dst,
                                                  const int* __restrict__ ptr_d,
                                                  const int* __restrict__ ptr_s,
                                                  const int* __restrict__ blkbase_d,
                                                  const int* __restrict__ blkbase_s,
                                                  int* __restrict__ packed_d,
                                                  int* __restrict__ packed_s,
                                                  int E, int nbkt) {
  __shared__ int hd[256], hs[256], bd[256], bs2[256];
  int t = threadIdx.x;
  if (t < nbkt) {
    bd[t]  = ptr_d[t] + blkbase_d[blockIdx.x * 256 + t];
    bs2[t] = ptr_s[t] + blkbase_s[blockIdx.x * 256 + t];
  }
  hd[t] = 0; hs[t] = 0;
  __syncthreads();
  int chunk = (E + gridDim.x - 1) / gridDim.x;
  int lo = blockIdx.x * chunk, hi = min(lo + chunk, E);
  for (int e = lo + t; e < hi; e += 256) {
    int s = src[e], d = dst[e];
    int b1 = d >> BSH;
    int r1 = atomicAdd(&hd[b1], 1);
    packed_d[bd[b1] + r1] = ((d & (BSZ - 1)) << 17) | s;
    int b2 = s >> BSH;
    int r2 = atomicAdd(&hs[b2], 1);
    packed_s[bs2[b2] + r2] = s & (BSZ - 1);
  }
}

// ---------------- fine pass (dst): row_end + CSR ----------------
__global__ __launch_bounds__(256) void k_fine_dst(const int* __restrict__ packed_d,
                                                  const int* __restrict__ ptr_d,
                                                  int* __restrict__ row_end,
                                                  int* __restrict__ csr, int N) {
  __shared__ int hist[512], excl[512], ps[256];
  int b = blockIdx.x, t = threadIdx.x;
  int lo = ptr_d[b], hi = ptr_d[b + 1];
  hist[t] = 0; hist[t + 256] = 0;
  __syncthreads();
  for (int e = lo + t; e < hi; e += 256)
    atomicAdd(&hist[packed_d[e] >> 17], 1);
  __syncthreads();
  int a0 = hist[2 * t], a1 = hist[2 * t + 1];
  ps[t] = a0 + a1;
  __syncthreads();
  for (int off = 1; off < 256; off <<= 1) {
    int a = (t >= off) ? ps[t - off] : 0;
    __syncthreads();
    ps[t] += a;
    __syncthreads();
  }
  int exc = ps[t] - (a0 + a1);
  excl[2 * t] = exc;
  excl[2 * t + 1] = exc + a0;
  int nbase = b << BSH;
  if (nbase + 2 * t < N)     row_end[nbase + 2 * t]     = lo + exc + a0;
  if (nbase + 2 * t + 1 < N) row_end[nbase + 2 * t + 1] = lo + exc + a0 + a1;
  __syncthreads();
  hist[t] = 0; hist[t + 256] = 0;
  __syncthreads();
  for (int e = lo + t; e < hi; e += 256) {
    int p = packed_d[e];
    int dlow = p >> 17, s = p & 0x1FFFF;
    int r = atomicAdd(&hist[dlow], 1);
    csr[lo + excl[dlow] + r] = s;
  }
}

// ---------------- fine pass (src): norm_src = rsqrt(max(deg_out,1)) ----------
__global__ __launch_bounds__(256) void k_fine_src(const int* __restrict__ packed_s,
                                                  const int* __restrict__ ptr_s,
                                                  float* __restrict__ norm_src, int N) {
  __shared__ int hist[512];
  int b = blockIdx.x, t = threadIdx.x;
  int lo = ptr_s[b], hi = ptr_s[b + 1];
  hist[t] = 0; hist[t + 256] = 0;
  __syncthreads();
  for (int e = lo + t; e < hi; e += 256)
    atomicAdd(&hist[packed_s[e]], 1);
  __syncthreads();
  int nbase = b << BSH;
  for (int i = t; i < BSZ; i += 256)
    if (nbase + i < N)
      norm_src[nbase + i] = rsqrtf(fmaxf((float)hist[i], 1.0f));
}

// ---------------- prep: Wt[n][k] = (half)W[k][n] for W1,W2 ----------------
__global__ __launch_bounds__(256) void k_prep(const float* __restrict__ W1,
                                              const float* __restrict__ W2,
                                              _Float16* __restrict__ Wt1,
                                              _Float16* __restrict__ Wt2) {
  int idx = blockIdx.x * 256 + threadIdx.x;   // grid 128 -> 32768 threads
  int m = idx >> 14;
  int i = idx & 16383;
  int k = i >> 7, n = i & 127;
  const float* W = m ? W2 : W1;
  _Float16* Wt = m ? Wt2 : Wt1;
  Wt[n * 128 + k] = (_Float16)W[i];  // i == k*128+n
}

// ---------------- MFMA GEMM (fp32 input): C(half) = (scale*A)@W ----------------
__global__ __launch_bounds__(256) void k_gemm1(const float* __restrict__ A,
                                               const _Float16* __restrict__ Wt,
                                               const float* __restrict__ scale,
                                               _Float16* __restrict__ C, int N) {
  __shared__ _Float16 As[64][136];
  __shared__ _Float16 Cs[64][128];
  const int r0 = blockIdx.x * 64;
  const int t = threadIdx.x;
  for (int i = t; i < 64 * 32; i += 256) {
    int r = i >> 5, c4 = i & 31;
    float4 v = {0.f, 0.f, 0.f, 0.f};
    if (r0 + r < N) {
      v = ((const float4*)A)[(size_t)(r0 + r) * 32 + c4];
      float s = scale[r0 + r];
      v.x *= s; v.y *= s; v.z *= s; v.w *= s;
    }
    half4v h = {(_Float16)v.x, (_Float16)v.y, (_Float16)v.z, (_Float16)v.w};
    *(half4v*)&As[r][c4 * 4] = h;
  }
  __syncthreads();
  const int w = t >> 6, l = t & 63;
  const int c = l & 15, quad = l >> 4;
  f32x4 acc[8];
#pragma unroll
  for (int nt = 0; nt < 8; ++nt) acc[nt] = (f32x4){0.f, 0.f, 0.f, 0.f};
#pragma unroll
  for (int kc = 0; kc < 4; ++kc) {
    half8 a = *(const half8*)&As[w * 16 + c][kc * 32 + quad * 8];
#pragma unroll
    for (int nt = 0; nt < 8; ++nt) {
      half8 b = *(const half8*)&Wt[(size_t)(nt * 16 + c) * 128 + kc * 32 + quad * 8];
      acc[nt] = __builtin_amdgcn_mfma_f32_16x16x32_f16(a, b, acc[nt], 0, 0, 0);
    }
  }
#pragma unroll
  for (int nt = 0; nt < 8; ++nt)
#pragma unroll
    for (int r = 0; r < 4; ++r)
      Cs[w * 16 + quad * 4 + r][nt * 16 + c] = (_Float16)acc[nt][r];
  __syncthreads();
  for (int i = t; i < 64 * 16; i += 256) {
    int r = i >> 4, c8 = i & 15;
    if (r0 + r < N)
      ((half8*)C)[(size_t)(r0 + r) * 16 + c8] = *(half8*)&Cs[r][c8 * 8];
  }
}

// ---------------- MFMA GEMM (fp16 pre-scaled input): C(half) = A@W -----------
__global__ __launch_bounds__(256) void k_gemm2(const _Float16* __restrict__ A,
                                               const _Float16* __restrict__ Wt,
                                               _Float16* __restrict__ C, int N) {
  __shared__ _Float16 As[64][136];
  __shared__ _Float16 Cs[64][128];
  const int r0 = blockIdx.x * 64;
  const int t = threadIdx.x;
  for (int i = t; i < 64 * 16; i += 256) {
    int r = i >> 4, c8 = i & 15;
    half8 v = {0, 0, 0, 0, 0, 0, 0, 0};
    if (r0 + r < N) v = ((const half8*)A)[(size_t)(r0 + r) * 16 + c8];
    *(half8*)&As[r][c8 * 8] = v;
  }
  __syncthreads();
  const int w = t >> 6, l = t & 63;
  const int c = l & 15, quad = l >> 4;
  f32x4 acc[8];
#pragma unroll
  for (int nt = 0; nt < 8; ++nt) acc[nt] = (f32x4){0.f, 0.f, 0.f, 0.f};
#pragma unroll
  for (int kc = 0; kc < 4; ++kc) {
    half8 a = *(const half8*)&As[w * 16 + c][kc * 32 + quad * 8];
#pragma unroll
    for (int nt = 0; nt < 8; ++nt) {
      half8 b = *(const half8*)&Wt[(size_t)(nt * 16 + c) * 128 + kc * 32 + quad * 8];
      acc[nt] = __builtin_amdgcn_mfma_f32_16x16x32_f16(a, b, acc[nt], 0, 0, 0);
    }
  }
#pragma unroll
  for (int nt = 0; nt < 8; ++nt)
#pragma unroll
    for (int r = 0; r < 4; ++r)
      Cs[w * 16 + quad * 4 + r][nt * 16 + c] = (_Float16)acc[nt][r];
  __syncthreads();
  for (int i = t; i < 64 * 16; i += 256) {
    int r = i >> 4, c8 = i & 15;
    if (r0 + r < N)
      ((half8*)C)[(size_t)(r0 + r) * 16 + c8] = *(half8*)&Cs[r][c8 * 8];
  }
}

// ---------------- gather core ----------------
// wave = 1 dst node; lane = (eg in [0,4)) x (cg in [0,16)).
// csr hoisted 64-at-a-time (coalesced), distributed via shfl; 4 rows in
// flight per lane (16 edges/iter). acc in fp32 via v_dot2_f32_f16.
#define FDOT2_ROW(u)                                                        \
  _Pragma("unroll")                                                         \
  for (int k = 0; k < 4; ++k) {                                             \
    acc[2 * k]     = __builtin_amdgcn_fdot2((u).h[k], c10, acc[2 * k], false); \
    acc[2 * k + 1] = __builtin_amdgcn_fdot2((u).h[k], c01, acc[2 * k + 1], false); \
  }

__device__ __forceinline__ void gather_core(const half8* __restrict__ P8,
                                            const int* __restrict__ csr,
                                            int start, int end, int cg, int eg,
                                            int lane, float* acc) {
  const half2v c10 = {(_Float16)1.0f, (_Float16)0.0f};
  const half2v c01 = {(_Float16)0.0f, (_Float16)1.0f};
  for (int s0 = start; s0 < end; s0 += 64) {
    int cnt = min(64, end - s0);
    int idx = (s0 + lane < end) ? csr[s0 + lane] : 0;
    int base = 0;
    for (; base + 16 <= cnt; base += 16) {
      int i0 = __shfl(idx, base + eg);
      int i1 = __shfl(idx, base + 4 + eg);
      int i2 = __shfl(idx, base + 8 + eg);
      int i3 = __shfl(idx, base + 12 + eg);
      H8 u0, u1, u2, u3;
      u0.v = P8[(size_t)i0 * 16 + cg];
      u1.v = P8[(size_t)i1 * 16 + cg];
      u2.v = P8[(size_t)i2 * 16 + cg];
      u3.v = P8[(size_t)i3 * 16 + cg];
      FDOT2_ROW(u0) FDOT2_ROW(u1) FDOT2_ROW(u2) FDOT2_ROW(u3)
    }
    for (; base + 4 <= cnt; base += 4) {
      int i0 = __shfl(idx, base + eg);
      H8 u0;
      u0.v = P8[(size_t)i0 * 16 + cg];
      FDOT2_ROW(u0)
    }
    if (base < cnt) {  // 1-3 tail edges
      int j = min(base + eg, cnt - 1);
      int i0 = __shfl(idx, j);
      if (base + eg < cnt) {
        H8 u0;
        u0.v = P8[(size_t)i0 * 16 + cg];
        FDOT2_ROW(u0)
      }
    }
  }
#pragma unroll
  for (int j = 0; j < 8; ++j) {
    acc[j] += __shfl_xor(acc[j], 16);
    acc[j] += __shfl_xor(acc[j], 32);
  }
}

// gather 1: h1' = norm_src * relu(agg*nd + b), fp16 out
__global__ __launch_bounds__(256) void k_gather1(const half8* __restrict__ P8,
                                                 const int* __restrict__ row_end,
                                                 const int* __restrict__ csr,
                                                 const float* __restrict__ bias,
                                                 const float* __restrict__ norm_src,
                                                 half2v* __restrict__ outH, int N) {
  int wid = (blockIdx.x * 256 + threadIdx.x) >> 6;
  if (wid >= N) return;
  int lane = threadIdx.x & 63;
  int cg = lane & 15, eg = lane >> 4;
  int end = row_end[wid];
  int start = (wid == 0) ? 0 : row_end[wid - 1];
  float acc[8] = {0.f, 0.f, 0.f, 0.f, 0.f, 0.f, 0.f, 0.f};
  gather_core(P8, csr, start, end, cg, eg, lane, acc);
  float nd = rsqrtf(fmaxf((float)(end - start), 1.0f));
  float ns = norm_src[wid];
  float2 b = ((const float2*)bias)[cg * 4 + eg];
  half2v o = {(_Float16)(fmaxf(acc[eg * 2] * nd + b.x, 0.f) * ns),
              (_Float16)(fmaxf(acc[eg * 2 + 1] * nd + b.y, 0.f) * ns)};
  outH[(size_t)wid * 64 + cg * 4 + eg] = o;
}

// gather 2: h2 = relu(agg*nd + b), fp32 out
__global__ __launch_bounds__(256) void k_gather2(const half8* __restrict__ P8,
                                                 const int* __restrict__ row_end,
                                                 const int* __restrict__ csr,
                                                 const float* __restrict__ bias,
                                                 float2* __restrict__ outH, int N) {
  int wid = (blockIdx.x * 256 + threadIdx.x) >> 6;
  if (wid >= N) return;
  int lane = threadIdx.x & 63;
  int cg = lane & 15, eg = lane >> 4;
  int end = row_end[wid];
  int start = (wid == 0) ? 0 : row_end[wid - 1];
  float acc[8] = {0.f, 0.f, 0.f, 0.f, 0.f, 0.f, 0.f, 0.f};
  gather_core(P8, csr, start, end, cg, eg, lane, acc);
  float nd = rsqrtf(fmaxf((float)(end - start), 1.0f));
  float2 b = ((const float2*)bias)[cg * 4 + eg];
  float2 o;
  o.x = fmaxf(acc[eg * 2] * nd + b.x, 0.f);
  o.y = fmaxf(acc[eg * 2 + 1] * nd + b.y, 0.f);
  outH[(size_t)wid * 64 + cg * 4 + eg] = o;
}

// ---------------- segment-sum pooling over sorted graph_id ----------------
__global__ __launch_bounds__(256) void k_pool(const float* __restrict__ H,
                                              const int* __restrict__ gptr,
                                              float* __restrict__ pool) {
  int g = blockIdx.x >> 3, chunk = blockIdx.x & 7;
  int col = threadIdx.x & 127, rpar = threadIdx.x >> 7;
  int s = gptr[g], e = gptr[g + 1];
  float acc = 0.0f;
  for (int r = s + chunk * 2 + rpar; r < e; r += 16)
    acc += H[(size_t)r * D + col];
  __shared__ float red[256];
  red[threadIdx.x] = acc;
  __syncthreads();
  if (rpar == 0) atomicAdd(&pool[g * D + col], acc + red[threadIdx.x + 128]);
}

// ---------------- readout MLP ----------------
__global__ __launch_bounds__(128) void k_readout(const float* __restrict__ pool,
                                                 const int* __restrict__ gptr,
                                                 const float* __restrict__ Wr1,
                                                 const float* __restrict__ br1,
                                                 const float* __restrict__ Wr2,
                                                 const float* __restrict__ br2,
                                                 float* __restrict__ out) {
  int g = blockIdx.x;
  int j = threadIdx.x;
  __shared__ float hg[D];
  __shared__ float t1[D];
  float cnt = fmaxf((float)(gptr[g + 1] - gptr[g]), 1.0f);
  hg[j] = pool[(size_t)g * D + j] / cnt;
  __syncthreads();
  float a = br1[j];
  for (int k = 0; k < D; ++k) a += hg[k] * Wr1[(size_t)k * D + j];
  t1[j] = fmaxf(a, 0.0f);
  __syncthreads();
  float b = br2[j];
  for (int k = 0; k < D; ++k) b += t1[k] * Wr2[(size_t)k * D + j];
  out[(size_t)g * D + j] = b;
}

extern "C" void kernel_launch(void* const* d_in, const int* in_sizes, int n_in,
                              void* d_out, int out_size, void* d_ws, size_t ws_size,
                              hipStream_t stream) {
  const float* x   = (const float*)d_in[0];
  const int* edge  = (const int*)d_in[1];
  const int* gid   = (const int*)d_in[2];
  const float* W1  = (const float*)d_in[4];
  const float* b1  = (const float*)d_in[5];
  const float* W2  = (const float*)d_in[6];
  const float* b2  = (const float*)d_in[7];
  const float* Wr1 = (const float*)d_in[8];
  const float* br1 = (const float*)d_in[9];
  const float* Wr2 = (const float*)d_in[10];
  const float* br2 = (const float*)d_in[11];

  const int N = in_sizes[0] / D;   // 100000
  const int E = in_sizes[1] / 2;   // 1600000
  const int* src = edge;
  const int* dst = edge + E;
  const int nbkt = (N + BSZ - 1) >> BSH;  // 196

  // workspace layout
  float* bufA     = (float*)d_ws;                    // P (half N*128) lives here
  float* bufB     = bufA + (size_t)N * D;            // h1' (half N*128) lives here
  int* row_end    = (int*)(bufB + (size_t)N * D);    // N
  int* csr        = row_end + N;                     // E
  float* norm_src = (float*)(csr + E);               // N
  float* pool     = norm_src + N;                    // 64*128
  int* gptr       = (int*)(pool + 64 * D);           // 65
  int* cnt_d      = gptr + 65;                       // 256
  int* cnt_s      = cnt_d + 256;                     // 256
  int* ptr_d      = cnt_s + 256;                     // 257
  int* ptr_s      = ptr_d + 257;                     // 257
  _Float16* Wt1   = (_Float16*)(ptr_s + 257);        // 128*128 halves
  _Float16* Wt2   = Wt1 + 128 * 128;                 // 128*128 halves
  // temporaries aliasing bufA (all consumed before gemm1 writes P)
  int* packed_d   = (int*)bufA;                      // E
  int* packed_s   = packed_d + E;                    // E
  int* blkbase_d  = packed_s + E;                    // 256*256
  int* blkbase_s  = blkbase_d + 256 * 256;           // 256*256
  size_t need = ((size_t)2 * N * D + 2 * N + E + 64 * D + 65 + 1026 + 8192)
                * sizeof(float);
  if (ws_size < need) return;

  float* out_g = (float*)d_out;      // 64*128
  float* h_out = out_g + 64 * D;     // N*128

  _Float16* P   = (_Float16*)bufA;
  _Float16* h1p = (_Float16*)bufB;

  hipMemsetAsync(cnt_d, 0, 512 * sizeof(int), stream);              // cnt_d + cnt_s
  hipMemsetAsync(pool, 0, 64 * D * sizeof(float), stream);

  // weight prep (independent)
  k_prep<<<128, 256, 0, stream>>>(W1, W2, Wt1, Wt2);

  // graph structure via two-level counting sort
  k_coarse<<<256, 256, 0, stream>>>(src, dst, cnt_d, cnt_s, blkbase_d, blkbase_s, E, nbkt);
  k_cscan<<<1, 256, 0, stream>>>(cnt_d, cnt_s, ptr_d, ptr_s, gid, gptr, nbkt, E, N);
  k_cscatter<<<256, 256, 0, stream>>>(src, dst, ptr_d, ptr_s, blkbase_d, blkbase_s,
                                      packed_d, packed_s, E, nbkt);
  k_fine_dst<<<nbkt, 256, 0, stream>>>(packed_d, ptr_d, row_end, csr, N);
  k_fine_src<<<nbkt, 256, 0, stream>>>(packed_s, ptr_s, norm_src, N);

  const int gemm_grid = (N + 63) / 64;

  // layer 1
  k_gemm1<<<gemm_grid, 256, 0, stream>>>(x, Wt1, norm_src, P, N);
  k_gather1<<<(N * 64 + 255) / 256, 256, 0, stream>>>(
      (const half8*)P, row_end, csr, b1, norm_src, (half2v*)h1p, N);

  // layer 2
  k_gemm2<<<gemm_grid, 256, 0, stream>>>(h1p, Wt2, P, N);
  k_gather2<<<(N * 64 + 255) / 256, 256, 0, stream>>>(
      (const half8*)P, row_end, csr, b2, (float2*)h_out, N);

  // pooling + readout
  k_pool<<<64 * 8, 256, 0, stream>>>(h_out, gptr, pool);
  k_readout<<<64, 128, 0, stream>>>(pool, gptr, Wr1, br1, Wr2, br2, out_g);
}

// Round 8
// 406.716 us; speedup vs baseline: 15.4089x; 1.0419x over previous
//
#include <hip/hip_runtime.h>
#include <math.h>

// GCN: h1 = relu(norm_dst * A * (norm_src * x) @ W1 + b1)
//      h2 = relu(norm_dst * A * (norm_src * h1) @ W2 + b2)
//      hg = mean_per_graph(h2); out = relu(hg@Wr1+br1)@Wr2+br2
// d_out = [out (64*128) | h2 (N*128)]
//
// R2: scatter-atomic SpMM -> CSR-by-dst + register gather (fused norm/bias/relu).
// R3: single-block scan -> 3-phase hierarchical scan.
// R4: degree/bucket random atomics -> two-level counting sort (LDS histograms).
// R5: fp16 pipeline: mfma_f32_16x16x32_f16 GEMMs, fp16 P/h1' (row 512B->256B).
// R6: gather (4 edges x 16 col-groups)/wave, fdot2 accumulation, bsearch gptr.
// R7: gather csr hoist + 4 rows in flight; cscatter single-pass via saved bases.
// R8: gather accumulates in packed fp16 (v_pk_add_f16, 1 op per 2 cols vs
//     2 fdot2) with fp32 cross-lane combine; fine_dst+fine_src merged into one
//     dispatch; memsets folded into k_prep. Dispatch count 14 -> 11.
// Assumes N <= 131072 (src fits 17 bits in packing).

#define D 128
#define BSH 9
#define BSZ 512

typedef _Float16 half8 __attribute__((ext_vector_type(8)));
typedef _Float16 half4v __attribute__((ext_vector_type(4)));
typedef _Float16 half2v __attribute__((ext_vector_type(2)));
typedef float f32x4 __attribute__((ext_vector_type(4)));

union H8 { half8 v; half2v h[4]; };

// ---------------- coarse histogram + per-block bucket bases ----------------
__global__ __launch_bounds__(256) void k_coarse(const int* __restrict__ src,
                                                const int* __restrict__ dst,
                                                int* __restrict__ cnt_d,
                                                int* __restrict__ cnt_s,
                                                int* __restrict__ blkbase_d,
                                                int* __restrict__ blkbase_s,
                                                int E, int nbkt) {
  __shared__ int hd[256], hs[256];
  int t = threadIdx.x;
  hd[t] = 0; hs[t] = 0;
  __syncthreads();
  int chunk = (E + gridDim.x - 1) / gridDim.x;
  int lo = blockIdx.x * chunk, hi = min(lo + chunk, E);
  for (int e = lo + t; e < hi; e += 256) {
    atomicAdd(&hd[dst[e] >> BSH], 1);
    atomicAdd(&hs[src[e] >> BSH], 1);
  }
  __syncthreads();
  if (t < nbkt) {
    int c = hd[t];
    blkbase_d[blockIdx.x * 256 + t] = c ? atomicAdd(&cnt_d[t], c) : 0;
    c = hs[t];
    blkbase_s[blockIdx.x * 256 + t] = c ? atomicAdd(&cnt_s[t], c) : 0;
  }
}

// ---------------- scan coarse counts -> ptrs; fused gptr bsearch ----------------
__global__ __launch_bounds__(256) void k_cscan(const int* __restrict__ cnt_d,
                                               const int* __restrict__ cnt_s,
                                               int* __restrict__ ptr_d,
                                               int* __restrict__ ptr_s,
                                               const int* __restrict__ gid,
                                               int* __restrict__ gptr,
                                               int nbkt, int E, int N) {
  __shared__ int sh[256];
  int t = threadIdx.x;
  int v = (t < nbkt) ? cnt_d[t] : 0;
  sh[t] = v;
  __syncthreads();
  for (int off = 1; off < 256; off <<= 1) {
    int a = (t >= off) ? sh[t - off] : 0;
    __syncthreads();
    sh[t] += a;
    __syncthreads();
  }
  if (t < nbkt) ptr_d[t] = sh[t] - v;
  if (t == 0) ptr_d[nbkt] = E;
  __syncthreads();
  v = (t < nbkt) ? cnt_s[t] : 0;
  sh[t] = v;
  __syncthreads();
  for (int off = 1; off < 256; off <<= 1) {
    int a = (t >= off) ? sh[t - off] : 0;
    __syncthreads();
    sh[t] += a;
    __syncthreads();
  }
  if (t < nbkt) ptr_s[t] = sh[t] - v;
  if (t == 0) ptr_s[nbkt] = E;
  // gptr[g] = lower_bound(gid, g), g in [0,64]
  if (t <= 64) {
    int lo = 0, hi = N;
    while (lo < hi) {
      int m = (lo + hi) >> 1;
      if (gid[m] < t) lo = m + 1; else hi = m;
    }
    gptr[t] = lo;
  }
}

// ---------------- coarse scatter (single pass; bases precomputed) ----------------
__global__ __launch_bounds__(256) void k_cscatter(const int* __restrict__ src,
                                                  const int* __restrict__ dst,
                                                  const int* __restrict__ ptr_d,
                                                  const int* __restrict__ ptr_s,
                                                  const int* __restrict__ blkbase_d,
                                                  const int* __restrict__ blkbase_s,
                                                  int* __restrict__ packed_d,
                                                  int* __restrict__ packed_s,
                                                  int E, int nbkt) {
  __shared__ int hd[256], hs[256], bd[256], bs2[256];
  int t = threadIdx.x;
  if (t < nbkt) {
    bd[t]  = ptr_d[t] + blkbase_d[blockIdx.x * 256 + t];
    bs2[t] = ptr_s[t] + blkbase_s[blockIdx.x * 256 + t];
  }
  hd[t] = 0; hs[t] = 0;
  __syncthreads();
  int chunk = (E + gridDim.x - 1) / gridDim.x;
  int lo = blockIdx.x * chunk, hi = min(lo + chunk, E);
  for (int e = lo + t; e < hi; e += 256) {
    int s = src[e], d = dst[e];
    int b1 = d >> BSH;
    int r1 = atomicAdd(&hd[b1], 1);
    packed_d[bd[b1] + r1] = ((d & (BSZ - 1)) << 17) | s;
    int b2 = s >> BSH;
    int r2 = atomicAdd(&hs[b2], 1);
    packed_s[bs2[b2] + r2] = s & (BSZ - 1);
  }
}

// ---------------- merged fine pass: blocks [0,nbkt) dst, [nbkt,2*nbkt) src ----
__global__ __launch_bounds__(256) void k_fine(const int* __restrict__ packed_d,
                                              const int* __restrict__ ptr_d,
                                              int* __restrict__ row_end,
                                              int* __restrict__ csr,
                                              const int* __restrict__ packed_s,
                                              const int* __restrict__ ptr_s,
                                              float* __restrict__ norm_src,
                                              int N, int nbkt) {
  __shared__ int hist[512], excl[512], ps[256];
  int t = threadIdx.x;
  if (blockIdx.x >= nbkt) {
    // ---- src side: norm_src = rsqrt(max(deg_out,1)) ----
    int b = blockIdx.x - nbkt;
    int lo = ptr_s[b], hi = ptr_s[b + 1];
    hist[t] = 0; hist[t + 256] = 0;
    __syncthreads();
    for (int e = lo + t; e < hi; e += 256)
      atomicAdd(&hist[packed_s[e]], 1);
    __syncthreads();
    int nbase = b << BSH;
    for (int i = t; i < BSZ; i += 256)
      if (nbase + i < N)
        norm_src[nbase + i] = rsqrtf(fmaxf((float)hist[i], 1.0f));
    return;
  }
  // ---- dst side: row_end + CSR ----
  int b = blockIdx.x;
  int lo = ptr_d[b], hi = ptr_d[b + 1];
  hist[t] = 0; hist[t + 256] = 0;
  __syncthreads();
  for (int e = lo + t; e < hi; e += 256)
    atomicAdd(&hist[packed_d[e] >> 17], 1);
  __syncthreads();
  int a0 = hist[2 * t], a1 = hist[2 * t + 1];
  ps[t] = a0 + a1;
  __syncthreads();
  for (int off = 1; off < 256; off <<= 1) {
    int a = (t >= off) ? ps[t - off] : 0;
    __syncthreads();
    ps[t] += a;
    __syncthreads();
  }
  int exc = ps[t] - (a0 + a1);
  excl[2 * t] = exc;
  excl[2 * t + 1] = exc + a0;
  int nbase = b << BSH;
  if (nbase + 2 * t < N)     row_end[nbase + 2 * t]     = lo + exc + a0;
  if (nbase + 2 * t + 1 < N) row_end[nbase + 2 * t + 1] = lo + exc + a0 + a1;
  __syncthreads();
  hist[t] = 0; hist[t + 256] = 0;
  __syncthreads();
  for (int e = lo + t; e < hi; e += 256) {
    int p = packed_d[e];
    int dlow = p >> 17, s = p & 0x1FFFF;
    int r = atomicAdd(&hist[dlow], 1);
    csr[lo + excl[dlow] + r] = s;
  }
}

// ---------------- prep: Wt transpose + zero cnt/pool ----------------
__global__ __launch_bounds__(256) void k_prep(const float* __restrict__ W1,
                                              const float* __restrict__ W2,
                                              _Float16* __restrict__ Wt1,
                                              _Float16* __restrict__ Wt2,
                                              int* __restrict__ cnt_d,
                                              float* __restrict__ pool) {
  if (blockIdx.x == 128) {
    int t = threadIdx.x;
    cnt_d[t] = 0; cnt_d[t + 256] = 0;  // cnt_d + cnt_s (adjacent)
    for (int i = t; i < 64 * D; i += 256) pool[i] = 0.0f;
    return;
  }
  int idx = blockIdx.x * 256 + threadIdx.x;
  int m = idx >> 14;
  int i = idx & 16383;
  int k = i >> 7, n = i & 127;
  const float* W = m ? W2 : W1;
  _Float16* Wt = m ? Wt2 : Wt1;
  Wt[n * 128 + k] = (_Float16)W[i];  // i == k*128+n
}

// ---------------- MFMA GEMM (fp32 input): C(half) = (scale*A)@W ----------------
__global__ __launch_bounds__(256) void k_gemm1(const float* __restrict__ A,
                                               const _Float16* __restrict__ Wt,
                                               const float* __restrict__ scale,
                                               _Float16* __restrict__ C, int N) {
  __shared__ _Float16 As[64][136];
  __shared__ _Float16 Cs[64][128];
  const int r0 = blockIdx.x * 64;
  const int t = threadIdx.x;
  for (int i = t; i < 64 * 32; i += 256) {
    int r = i >> 5, c4 = i & 31;
    float4 v = {0.f, 0.f, 0.f, 0.f};
    if (r0 + r < N) {
      v = ((const float4*)A)[(size_t)(r0 + r) * 32 + c4];
      float s = scale[r0 + r];
      v.x *= s; v.y *= s; v.z *= s; v.w *= s;
    }
    half4v h = {(_Float16)v.x, (_Float16)v.y, (_Float16)v.z, (_Float16)v.w};
    *(half4v*)&As[r][c4 * 4] = h;
  }
  __syncthreads();
  const int w = t >> 6, l = t & 63;
  const int c = l & 15, quad = l >> 4;
  f32x4 acc[8];
#pragma unroll
  for (int nt = 0; nt < 8; ++nt) acc[nt] = (f32x4){0.f, 0.f, 0.f, 0.f};
#pragma unroll
  for (int kc = 0; kc < 4; ++kc) {
    half8 a = *(const half8*)&As[w * 16 + c][kc * 32 + quad * 8];
#pragma unroll
    for (int nt = 0; nt < 8; ++nt) {
      half8 b = *(const half8*)&Wt[(size_t)(nt * 16 + c) * 128 + kc * 32 + quad * 8];
      acc[nt] = __builtin_amdgcn_mfma_f32_16x16x32_f16(a, b, acc[nt], 0, 0, 0);
    }
  }
#pragma unroll
  for (int nt = 0; nt < 8; ++nt)
#pragma unroll
    for (int r = 0; r < 4; ++r)
      Cs[w * 16 + quad * 4 + r][nt * 16 + c] = (_Float16)acc[nt][r];
  __syncthreads();
  for (int i = t; i < 64 * 16; i += 256) {
    int r = i >> 4, c8 = i & 15;
    if (r0 + r < N)
      ((half8*)C)[(size_t)(r0 + r) * 16 + c8] = *(half8*)&Cs[r][c8 * 8];
  }
}

// ---------------- MFMA GEMM (fp16 pre-scaled input): C(half) = A@W -----------
__global__ __launch_bounds__(256) void k_gemm2(const _Float16* __restrict__ A,
                                               const _Float16* __restrict__ Wt,
                                               _Float16* __restrict__ C, int N) {
  __shared__ _Float16 As[64][136];
  __shared__ _Float16 Cs[64][128];
  const int r0 = blockIdx.x * 64;
  const int t = threadIdx.x;
  for (int i = t; i < 64 * 16; i += 256) {
    int r = i >> 4, c8 = i & 15;
    half8 v = {0, 0, 0, 0, 0, 0, 0, 0};
    if (r0 + r < N) v = ((const half8*)A)[(size_t)(r0 + r) * 16 + c8];
    *(half8*)&As[r][c8 * 8] = v;
  }
  __syncthreads();
  const int w = t >> 6, l = t & 63;
  const int c = l & 15, quad = l >> 4;
  f32x4 acc[8];
#pragma unroll
  for (int nt = 0; nt < 8; ++nt) acc[nt] = (f32x4){0.f, 0.f, 0.f, 0.f};
#pragma unroll
  for (int kc = 0; kc < 4; ++kc) {
    half8 a = *(const half8*)&As[w * 16 + c][kc * 32 + quad * 8];
#pragma unroll
    for (int nt = 0; nt < 8; ++nt) {
      half8 b = *(const half8*)&Wt[(size_t)(nt * 16 + c) * 128 + kc * 32 + quad * 8];
      acc[nt] = __builtin_amdgcn_mfma_f32_16x16x32_f16(a, b, acc[nt], 0, 0, 0);
    }
  }
#pragma unroll
  for (int nt = 0; nt < 8; ++nt)
#pragma unroll
    for (int r = 0; r < 4; ++r)
      Cs[w * 16 + quad * 4 + r][nt * 16 + c] = (_Float16)acc[nt][r];
  __syncthreads();
  for (int i = t; i < 64 * 16; i += 256) {
    int r = i >> 4, c8 = i & 15;
    if (r0 + r < N)
      ((half8*)C)[(size_t)(r0 + r) * 16 + c8] = *(half8*)&Cs[r][c8 * 8];
  }
}

// ---------------- gather core ----------------
// wave = 1 dst node; lane = (eg in [0,4)) x (cg in [0,16)).
// csr hoisted 64-at-a-time (coalesced), distributed via shfl; 4 rows in
// flight per lane. Accumulate packed fp16 (v_pk_add_f16; each lane's partial
// only sums ~deg/4 terms), cross-eg combine in fp32.
#define PK_ROW(u)                                                           \
  _Pragma("unroll")                                                         \
  for (int k = 0; k < 4; ++k) acch[k] += (u).h[k];

__device__ __forceinline__ void gather_core(const half8* __restrict__ P8,
                                            const int* __restrict__ csr,
                                            int start, int end, int cg, int eg,
                                            int lane, float* acc) {
  half2v acch[4] = {{(_Float16)0.f, (_Float16)0.f}, {(_Float16)0.f, (_Float16)0.f},
                    {(_Float16)0.f, (_Float16)0.f}, {(_Float16)0.f, (_Float16)0.f}};
  for (int s0 = start; s0 < end; s0 += 64) {
    int cnt = min(64, end - s0);
    int idx = (s0 + lane < end) ? csr[s0 + lane] : 0;
    int base = 0;
    for (; base + 16 <= cnt; base += 16) {
      int i0 = __shfl(idx, base + eg);
      int i1 = __shfl(idx, base + 4 + eg);
      int i2 = __shfl(idx, base + 8 + eg);
      int i3 = __shfl(idx, base + 12 + eg);
      H8 u0, u1, u2, u3;
      u0.v = P8[(size_t)i0 * 16 + cg];
      u1.v = P8[(size_t)i1 * 16 + cg];
      u2.v = P8[(size_t)i2 * 16 + cg];
      u3.v = P8[(size_t)i3 * 16 + cg];
      PK_ROW(u0) PK_ROW(u1) PK_ROW(u2) PK_ROW(u3)
    }
    for (; base + 4 <= cnt; base += 4) {
      int i0 = __shfl(idx, base + eg);
      H8 u0;
      u0.v = P8[(size_t)i0 * 16 + cg];
      PK_ROW(u0)
    }
    if (base < cnt) {  // 1-3 tail edges
      int j = min(base + eg, cnt - 1);
      int i0 = __shfl(idx, j);
      if (base + eg < cnt) {
        H8 u0;
        u0.v = P8[(size_t)i0 * 16 + cg];
        PK_ROW(u0)
      }
    }
  }
#pragma unroll
  for (int k = 0; k < 4; ++k) {
    acc[2 * k]     = (float)acch[k].x;
    acc[2 * k + 1] = (float)acch[k].y;
  }
#pragma unroll
  for (int j = 0; j < 8; ++j) {
    acc[j] += __shfl_xor(acc[j], 16);
    acc[j] += __shfl_xor(acc[j], 32);
  }
}

// gather 1: h1' = norm_src * relu(agg*nd + b), fp16 out
__global__ __launch_bounds__(256) void k_gather1(const half8* __restrict__ P8,
                                                 const int* __restrict__ row_end,
                                                 const int* __restrict__ csr,
                                                 const float* __restrict__ bias,
                                                 const float* __restrict__ norm_src,
                                                 half2v* __restrict__ outH, int N) {
  int wid = (blockIdx.x * 256 + threadIdx.x) >> 6;
  if (wid >= N) return;
  int lane = threadIdx.x & 63;
  int cg = lane & 15, eg = lane >> 4;
  int end = row_end[wid];
  int start = (wid == 0) ? 0 : row_end[wid - 1];
  float acc[8];
  gather_core(P8, csr, start, end, cg, eg, lane, acc);
  float nd = rsqrtf(fmaxf((float)(end - start), 1.0f));
  float ns = norm_src[wid];
  float2 b = ((const float2*)bias)[cg * 4 + eg];
  half2v o = {(_Float16)(fmaxf(acc[eg * 2] * nd + b.x, 0.f) * ns),
              (_Float16)(fmaxf(acc[eg * 2 + 1] * nd + b.y, 0.f) * ns)};
  outH[(size_t)wid * 64 + cg * 4 + eg] = o;
}

// gather 2: h2 = relu(agg*nd + b), fp32 out
__global__ __launch_bounds__(256) void k_gather2(const half8* __restrict__ P8,
                                                 const int* __restrict__ row_end,
                                                 const int* __restrict__ csr,
                                                 const float* __restrict__ bias,
                                                 float2* __restrict__ outH, int N) {
  int wid = (blockIdx.x * 256 + threadIdx.x) >> 6;
  if (wid >= N) return;
  int lane = threadIdx.x & 63;
  int cg = lane & 15, eg = lane >> 4;
  int end = row_end[wid];
  int start = (wid == 0) ? 0 : row_end[wid - 1];
  float acc[8];
  gather_core(P8, csr, start, end, cg, eg, lane, acc);
  float nd = rsqrtf(fmaxf((float)(end - start), 1.0f));
  float2 b = ((const float2*)bias)[cg * 4 + eg];
  float2 o;
  o.x = fmaxf(acc[eg * 2] * nd + b.x, 0.f);
  o.y = fmaxf(acc[eg * 2 + 1] * nd + b.y, 0.f);
  outH[(size_t)wid * 64 + cg * 4 + eg] = o;
}

// ---------------- segment-sum pooling over sorted graph_id ----------------
__global__ __launch_bounds__(256) void k_pool(const float* __restrict__ H,
                                              const int* __restrict__ gptr,
                                              float* __restrict__ pool) {
  int g = blockIdx.x >> 3, chunk = blockIdx.x & 7;
  int col = threadIdx.x & 127, rpar = threadIdx.x >> 7;
  int s = gptr[g], e = gptr[g + 1];
  float acc = 0.0f;
  for (int r = s + chunk * 2 + rpar; r < e; r += 16)
    acc += H[(size_t)r * D + col];
  __shared__ float red[256];
  red[threadIdx.x] = acc;
  __syncthreads();
  if (rpar == 0) atomicAdd(&pool[g * D + col], acc + red[threadIdx.x + 128]);
}

// ---------------- readout MLP ----------------
__global__ __launch_bounds__(128) void k_readout(const float* __restrict__ pool,
                                                 const int* __restrict__ gptr,
                                                 const float* __restrict__ Wr1,
                                                 const float* __restrict__ br1,
                                                 const float* __restrict__ Wr2,
                                                 const float* __restrict__ br2,
                                                 float* __restrict__ out) {
  int g = blockIdx.x;
  int j = threadIdx.x;
  __shared__ float hg[D];
  __shared__ float t1[D];
  float cnt = fmaxf((float)(gptr[g + 1] - gptr[g]), 1.0f);
  hg[j] = pool[(size_t)g * D + j] / cnt;
  __syncthreads();
  float a = br1[j];
  for (int k = 0; k < D; ++k) a += hg[k] * Wr1[(size_t)k * D + j];
  t1[j] = fmaxf(a, 0.0f);
  __syncthreads();
  float b = br2[j];
  for (int k = 0; k < D; ++k) b += t1[k] * Wr2[(size_t)k * D + j];
  out[(size_t)g * D + j] = b;
}

extern "C" void kernel_launch(void* const* d_in, const int* in_sizes, int n_in,
                              void* d_out, int out_size, void* d_ws, size_t ws_size,
                              hipStream_t stream) {
  const float* x   = (const float*)d_in[0];
  const int* edge  = (const int*)d_in[1];
  const int* gid   = (const int*)d_in[2];
  const float* W1  = (const float*)d_in[4];
  const float* b1  = (const float*)d_in[5];
  const float* W2  = (const float*)d_in[6];
  const float* b2  = (const float*)d_in[7];
  const float* Wr1 = (const float*)d_in[8];
  const float* br1 = (const float*)d_in[9];
  const float* Wr2 = (const float*)d_in[10];
  const float* br2 = (const float*)d_in[11];

  const int N = in_sizes[0] / D;   // 100000
  const int E = in_sizes[1] / 2;   // 1600000
  const int* src = edge;
  const int* dst = edge + E;
  const int nbkt = (N + BSZ - 1) >> BSH;  // 196

  // workspace layout
  float* bufA     = (float*)d_ws;                    // P (half N*128) lives here
  float* bufB     = bufA + (size_t)N * D;            // h1' (half N*128) lives here
  int* row_end    = (int*)(bufB + (size_t)N * D);    // N
  int* csr        = row_end + N;                     // E
  float* norm_src = (float*)(csr + E);               // N
  float* pool     = norm_src + N;                    // 64*128
  int* gptr       = (int*)(pool + 64 * D);           // 65
  int* cnt_d      = gptr + 65;                       // 256
  int* cnt_s      = cnt_d + 256;                     // 256 (adjacent to cnt_d)
  int* ptr_d      = cnt_s + 256;                     // 257
  int* ptr_s      = ptr_d + 257;                     // 257
  _Float16* Wt1   = (_Float16*)(ptr_s + 257);        // 128*128 halves
  _Float16* Wt2   = Wt1 + 128 * 128;                 // 128*128 halves
  // temporaries aliasing bufA (all consumed before gemm1 writes P)
  int* packed_d   = (int*)bufA;                      // E
  int* packed_s   = packed_d + E;                    // E
  int* blkbase_d  = packed_s + E;                    // 256*256
  int* blkbase_s  = blkbase_d + 256 * 256;           // 256*256
  size_t need = ((size_t)2 * N * D + 2 * N + E + 64 * D + 65 + 1026 + 8192)
                * sizeof(float);
  if (ws_size < need) return;

  float* out_g = (float*)d_out;      // 64*128
  float* h_out = out_g + 64 * D;     // N*128

  _Float16* P   = (_Float16*)bufA;
  _Float16* h1p = (_Float16*)bufB;

  // prep: Wt transpose + zero cnt_d/cnt_s/pool (block 128)
  k_prep<<<129, 256, 0, stream>>>(W1, W2, Wt1, Wt2, cnt_d, pool);

  // graph structure via two-level counting sort
  k_coarse<<<256, 256, 0, stream>>>(src, dst, cnt_d, cnt_s, blkbase_d, blkbase_s, E, nbkt);
  k_cscan<<<1, 256, 0, stream>>>(cnt_d, cnt_s, ptr_d, ptr_s, gid, gptr, nbkt, E, N);
  k_cscatter<<<256, 256, 0, stream>>>(src, dst, ptr_d, ptr_s, blkbase_d, blkbase_s,
                                      packed_d, packed_s, E, nbkt);
  k_fine<<<2 * nbkt, 256, 0, stream>>>(packed_d, ptr_d, row_end, csr,
                                       packed_s, ptr_s, norm_src, N, nbkt);

  const int gemm_grid = (N + 63) / 64;

  // layer 1
  k_gemm1<<<gemm_grid, 256, 0, stream>>>(x, Wt1, norm_src, P, N);
  k_gather1<<<(N * 64 + 255) / 256, 256, 0, stream>>>(
      (const half8*)P, row_end, csr, b1, norm_src, (half2v*)h1p, N);

  // layer 2
  k_gemm2<<<gemm_grid, 256, 0, stream>>>(h1p, Wt2, P, N);
  k_gather2<<<(N * 64 + 255) / 256, 256, 0, stream>>>(
      (const half8*)P, row_end, csr, b2, (float2*)h_out, N);

  // pooling + readout
  k_pool<<<64 * 8, 256, 0, stream>>>(h_out, gptr, pool);
  k_readout<<<64, 128, 0, stream>>>(pool, gptr, Wr1, br1, Wr2, br2, out_g);
}

// Round 9
// 402.698 us; speedup vs baseline: 15.5627x; 1.0100x over previous
//
#include <hip/hip_runtime.h>
#include <math.h>

// GCN: h1 = relu(norm_dst * A * (norm_src * x) @ W1 + b1)
//      h2 = relu(norm_dst * A * (norm_src * h1) @ W2 + b2)
//      hg = mean_per_graph(h2); out = relu(hg@Wr1+br1)@Wr2+br2
// d_out = [out (64*128) | h2 (N*128)]
//
// R2: scatter-atomic SpMM -> CSR-by-dst + register gather (fused norm/bias/relu).
// R4: degree/bucket random atomics -> two-level counting sort (LDS histograms).
// R5: fp16 pipeline: mfma_f32_16x16x32_f16 GEMMs, fp16 P/h1' (row 512B->256B).
// R6-R8: gather (4 edges x 16 col-groups)/wave, csr hoist, packed fp16 acc;
//        single-pass cscatter; merged fine; memsets folded into prep.
// R9: build-chain occupancy: coarse/cscatter 256x256 (1 wave/SIMD!) -> 512x512;
//     fine 512-thread blocks + LDS edge cache (histogram pass stages bucket,
//     scatter pass reads LDS, halving global reads). Gather is pinned at its
//     random-access floor (~60us, 3.9TB/s) across 4 structural variants.
// Assumes N <= 131072 (src fits 17 bits in packing).

#define D 128
#define BSH 9
#define BSZ 512
#define NBLK 512     // coarse/cscatter grid
#define ECAP 12288   // LDS edge cache entries (bucket avg ~8200, 45-sigma safe)

typedef _Float16 half8 __attribute__((ext_vector_type(8)));
typedef _Float16 half4v __attribute__((ext_vector_type(4)));
typedef _Float16 half2v __attribute__((ext_vector_type(2)));
typedef float f32x4 __attribute__((ext_vector_type(4)));

union H8 { half8 v; half2v h[4]; };

// ---------------- coarse histogram + per-block bucket bases ----------------
__global__ __launch_bounds__(512) void k_coarse(const int* __restrict__ src,
                                                const int* __restrict__ dst,
                                                int* __restrict__ cnt_d,
                                                int* __restrict__ cnt_s,
                                                int* __restrict__ blkbase_d,
                                                int* __restrict__ blkbase_s,
                                                int E, int nbkt) {
  __shared__ int hd[256], hs[256];
  int t = threadIdx.x;
  if (t < 256) { hd[t] = 0; hs[t] = 0; }
  __syncthreads();
  int chunk = (E + gridDim.x - 1) / gridDim.x;
  int lo = blockIdx.x * chunk, hi = min(lo + chunk, E);
  for (int e = lo + t; e < hi; e += 512) {
    atomicAdd(&hd[dst[e] >> BSH], 1);
    atomicAdd(&hs[src[e] >> BSH], 1);
  }
  __syncthreads();
  if (t < nbkt) {
    int c = hd[t];
    blkbase_d[blockIdx.x * 256 + t] = c ? atomicAdd(&cnt_d[t], c) : 0;
    c = hs[t];
    blkbase_s[blockIdx.x * 256 + t] = c ? atomicAdd(&cnt_s[t], c) : 0;
  }
}

// ---------------- scan coarse counts -> ptrs; fused gptr bsearch ----------------
__global__ __launch_bounds__(256) void k_cscan(const int* __restrict__ cnt_d,
                                               const int* __restrict__ cnt_s,
                                               int* __restrict__ ptr_d,
                                               int* __restrict__ ptr_s,
                                               const int* __restrict__ gid,
                                               int* __restrict__ gptr,
                                               int nbkt, int E, int N) {
  __shared__ int sh[256];
  int t = threadIdx.x;
  int v = (t < nbkt) ? cnt_d[t] : 0;
  sh[t] = v;
  __syncthreads();
  for (int off = 1; off < 256; off <<= 1) {
    int a = (t >= off) ? sh[t - off] : 0;
    __syncthreads();
    sh[t] += a;
    __syncthreads();
  }
  if (t < nbkt) ptr_d[t] = sh[t] - v;
  if (t == 0) ptr_d[nbkt] = E;
  __syncthreads();
  v = (t < nbkt) ? cnt_s[t] : 0;
  sh[t] = v;
  __syncthreads();
  for (int off = 1; off < 256; off <<= 1) {
    int a = (t >= off) ? sh[t - off] : 0;
    __syncthreads();
    sh[t] += a;
    __syncthreads();
  }
  if (t < nbkt) ptr_s[t] = sh[t] - v;
  if (t == 0) ptr_s[nbkt] = E;
  // gptr[g] = lower_bound(gid, g), g in [0,64]
  if (t <= 64) {
    int lo = 0, hi = N;
    while (lo < hi) {
      int m = (lo + hi) >> 1;
      if (gid[m] < t) lo = m + 1; else hi = m;
    }
    gptr[t] = lo;
  }
}

// ---------------- coarse scatter (single pass; bases precomputed) ----------------
__global__ __launch_bounds__(512) void k_cscatter(const int* __restrict__ src,
                                                  const int* __restrict__ dst,
                                                  const int* __restrict__ ptr_d,
                                                  const int* __restrict__ ptr_s,
                                                  const int* __restrict__ blkbase_d,
                                                  const int* __restrict__ blkbase_s,
                                                  int* __restrict__ packed_d,
                                                  int* __restrict__ packed_s,
                                                  int E, int nbkt) {
  __shared__ int hd[256], hs[256], bd[256], bs2[256];
  int t = threadIdx.x;
  if (t < nbkt) {
    bd[t]  = ptr_d[t] + blkbase_d[blockIdx.x * 256 + t];
    bs2[t] = ptr_s[t] + blkbase_s[blockIdx.x * 256 + t];
  }
  if (t < 256) { hd[t] = 0; hs[t] = 0; }
  __syncthreads();
  int chunk = (E + gridDim.x - 1) / gridDim.x;
  int lo = blockIdx.x * chunk, hi = min(lo + chunk, E);
  for (int e = lo + t; e < hi; e += 512) {
    int s = src[e], d = dst[e];
    int b1 = d >> BSH;
    int r1 = atomicAdd(&hd[b1], 1);
    packed_d[bd[b1] + r1] = ((d & (BSZ - 1)) << 17) | s;
    int b2 = s >> BSH;
    int r2 = atomicAdd(&hs[b2], 1);
    packed_s[bs2[b2] + r2] = s & (BSZ - 1);
  }
}

// ---------------- merged fine pass: blocks [0,nbkt) dst, [nbkt,2*nbkt) src ----
// 512 threads; dst side stages its bucket's packed edges in LDS during the
// histogram pass so the scatter pass avoids a second global read.
__global__ __launch_bounds__(512) void k_fine(const int* __restrict__ packed_d,
                                              const int* __restrict__ ptr_d,
                                              int* __restrict__ row_end,
                                              int* __restrict__ csr,
                                              const int* __restrict__ packed_s,
                                              const int* __restrict__ ptr_s,
                                              float* __restrict__ norm_src,
                                              int N, int nbkt) {
  __shared__ int hist[512];
  int t = threadIdx.x;
  if (blockIdx.x >= nbkt) {
    // ---- src side: norm_src = rsqrt(max(deg_out,1)) ----
    int b = blockIdx.x - nbkt;
    int lo = ptr_s[b], hi = ptr_s[b + 1];
    hist[t] = 0;
    __syncthreads();
    for (int e = lo + t; e < hi; e += 512)
      atomicAdd(&hist[packed_s[e]], 1);
    __syncthreads();
    int nbase = b << BSH;
    if (nbase + t < N)
      norm_src[nbase + t] = rsqrtf(fmaxf((float)hist[t], 1.0f));
    return;
  }
  // ---- dst side: row_end + CSR ----
  __shared__ int excl[512];
  __shared__ int ecache[ECAP];
  int b = blockIdx.x;
  int lo = ptr_d[b], hi = ptr_d[b + 1];
  hist[t] = 0;
  __syncthreads();
  for (int e = lo + t; e < hi; e += 512) {
    int p = packed_d[e];
    int off = e - lo;
    if (off < ECAP) ecache[off] = p;
    atomicAdd(&hist[p >> 17], 1);
  }
  __syncthreads();
  int v = hist[t];
  // inclusive scan of hist (512 entries, Hillis-Steele)
  for (int off = 1; off < 512; off <<= 1) {
    int a = (t >= off) ? hist[t - off] : 0;
    __syncthreads();
    hist[t] += a;
    __syncthreads();
  }
  excl[t] = hist[t] - v;
  int nbase = b << BSH;
  if (nbase + t < N) row_end[nbase + t] = lo + hist[t];
  __syncthreads();
  hist[t] = 0;  // reuse as rank counters
  __syncthreads();
  for (int e = lo + t; e < hi; e += 512) {
    int off = e - lo;
    int p = (off < ECAP) ? ecache[off] : packed_d[e];
    int dlow = p >> 17, s = p & 0x1FFFF;
    int r = atomicAdd(&hist[dlow], 1);
    csr[lo + excl[dlow] + r] = s;
  }
}

// ---------------- prep: Wt transpose + zero cnt/pool ----------------
__global__ __launch_bounds__(256) void k_prep(const float* __restrict__ W1,
                                              const float* __restrict__ W2,
                                              _Float16* __restrict__ Wt1,
                                              _Float16* __restrict__ Wt2,
                                              int* __restrict__ cnt_d,
                                              float* __restrict__ pool) {
  if (blockIdx.x == 128) {
    int t = threadIdx.x;
    cnt_d[t] = 0; cnt_d[t + 256] = 0;  // cnt_d + cnt_s (adjacent)
    for (int i = t; i < 64 * D; i += 256) pool[i] = 0.0f;
    return;
  }
  int idx = blockIdx.x * 256 + threadIdx.x;
  int m = idx >> 14;
  int i = idx & 16383;
  int k = i >> 7, n = i & 127;
  const float* W = m ? W2 : W1;
  _Float16* Wt = m ? Wt2 : Wt1;
  Wt[n * 128 + k] = (_Float16)W[i];  // i == k*128+n
}

// ---------------- MFMA GEMM (fp32 input): C(half) = (scale*A)@W ----------------
__global__ __launch_bounds__(256) void k_gemm1(const float* __restrict__ A,
                                               const _Float16* __restrict__ Wt,
                                               const float* __restrict__ scale,
                                               _Float16* __restrict__ C, int N) {
  __shared__ _Float16 As[64][136];
  __shared__ _Float16 Cs[64][128];
  const int r0 = blockIdx.x * 64;
  const int t = threadIdx.x;
  for (int i = t; i < 64 * 32; i += 256) {
    int r = i >> 5, c4 = i & 31;
    float4 v = {0.f, 0.f, 0.f, 0.f};
    if (r0 + r < N) {
      v = ((const float4*)A)[(size_t)(r0 + r) * 32 + c4];
      float s = scale[r0 + r];
      v.x *= s; v.y *= s; v.z *= s; v.w *= s;
    }
    half4v h = {(_Float16)v.x, (_Float16)v.y, (_Float16)v.z, (_Float16)v.w};
    *(half4v*)&As[r][c4 * 4] = h;
  }
  __syncthreads();
  const int w = t >> 6, l = t & 63;
  const int c = l & 15, quad = l >> 4;
  f32x4 acc[8];
#pragma unroll
  for (int nt = 0; nt < 8; ++nt) acc[nt] = (f32x4){0.f, 0.f, 0.f, 0.f};
#pragma unroll
  for (int kc = 0; kc < 4; ++kc) {
    half8 a = *(const half8*)&As[w * 16 + c][kc * 32 + quad * 8];
#pragma unroll
    for (int nt = 0; nt < 8; ++nt) {
      half8 b = *(const half8*)&Wt[(size_t)(nt * 16 + c) * 128 + kc * 32 + quad * 8];
      acc[nt] = __builtin_amdgcn_mfma_f32_16x16x32_f16(a, b, acc[nt], 0, 0, 0);
    }
  }
#pragma unroll
  for (int nt = 0; nt < 8; ++nt)
#pragma unroll
    for (int r = 0; r < 4; ++r)
      Cs[w * 16 + quad * 4 + r][nt * 16 + c] = (_Float16)acc[nt][r];
  __syncthreads();
  for (int i = t; i < 64 * 16; i += 256) {
    int r = i >> 4, c8 = i & 15;
    if (r0 + r < N)
      ((half8*)C)[(size_t)(r0 + r) * 16 + c8] = *(half8*)&Cs[r][c8 * 8];
  }
}

// ---------------- MFMA GEMM (fp16 pre-scaled input): C(half) = A@W -----------
__global__ __launch_bounds__(256) void k_gemm2(const _Float16* __restrict__ A,
                                               const _Float16* __restrict__ Wt,
                                               _Float16* __restrict__ C, int N) {
  __shared__ _Float16 As[64][136];
  __shared__ _Float16 Cs[64][128];
  const int r0 = blockIdx.x * 64;
  const int t = threadIdx.x;
  for (int i = t; i < 64 * 16; i += 256) {
    int r = i >> 4, c8 = i & 15;
    half8 v = {0, 0, 0, 0, 0, 0, 0, 0};
    if (r0 + r < N) v = ((const half8*)A)[(size_t)(r0 + r) * 16 + c8];
    *(half8*)&As[r][c8 * 8] = v;
  }
  __syncthreads();
  const int w = t >> 6, l = t & 63;
  const int c = l & 15, quad = l >> 4;
  f32x4 acc[8];
#pragma unroll
  for (int nt = 0; nt < 8; ++nt) acc[nt] = (f32x4){0.f, 0.f, 0.f, 0.f};
#pragma unroll
  for (int kc = 0; kc < 4; ++kc) {
    half8 a = *(const half8*)&As[w * 16 + c][kc * 32 + quad * 8];
#pragma unroll
    for (int nt = 0; nt < 8; ++nt) {
      half8 b = *(const half8*)&Wt[(size_t)(nt * 16 + c) * 128 + kc * 32 + quad * 8];
      acc[nt] = __builtin_amdgcn_mfma_f32_16x16x32_f16(a, b, acc[nt], 0, 0, 0);
    }
  }
#pragma unroll
  for (int nt = 0; nt < 8; ++nt)
#pragma unroll
    for (int r = 0; r < 4; ++r)
      Cs[w * 16 + quad * 4 + r][nt * 16 + c] = (_Float16)acc[nt][r];
  __syncthreads();
  for (int i = t; i < 64 * 16; i += 256) {
    int r = i >> 4, c8 = i & 15;
    if (r0 + r < N)
      ((half8*)C)[(size_t)(r0 + r) * 16 + c8] = *(half8*)&Cs[r][c8 * 8];
  }
}

// ---------------- gather core ----------------
// wave = 1 dst node; lane = (eg in [0,4)) x (cg in [0,16)).
// csr hoisted 64-at-a-time (coalesced), shfl distribute; 4 rows in flight per
// lane; packed fp16 accumulation (lane partial ~deg/4 terms), fp32 combine.
#define PK_ROW(u)                                                           \
  _Pragma("unroll")                                                         \
  for (int k = 0; k < 4; ++k) acch[k] += (u).h[k];

__device__ __forceinline__ void gather_core(const half8* __restrict__ P8,
                                            const int* __restrict__ csr,
                                            int start, int end, int cg, int eg,
                                            int lane, float* acc) {
  half2v acch[4] = {{(_Float16)0.f, (_Float16)0.f}, {(_Float16)0.f, (_Float16)0.f},
                    {(_Float16)0.f, (_Float16)0.f}, {(_Float16)0.f, (_Float16)0.f}};
  for (int s0 = start; s0 < end; s0 += 64) {
    int cnt = min(64, end - s0);
    int idx = (s0 + lane < end) ? csr[s0 + lane] : 0;
    int base = 0;
    for (; base + 16 <= cnt; base += 16) {
      int i0 = __shfl(idx, base + eg);
      int i1 = __shfl(idx, base + 4 + eg);
      int i2 = __shfl(idx, base + 8 + eg);
      int i3 = __shfl(idx, base + 12 + eg);
      H8 u0, u1, u2, u3;
      u0.v = P8[(size_t)i0 * 16 + cg];
      u1.v = P8[(size_t)i1 * 16 + cg];
      u2.v = P8[(size_t)i2 * 16 + cg];
      u3.v = P8[(size_t)i3 * 16 + cg];
      PK_ROW(u0) PK_ROW(u1) PK_ROW(u2) PK_ROW(u3)
    }
    for (; base + 4 <= cnt; base += 4) {
      int i0 = __shfl(idx, base + eg);
      H8 u0;
      u0.v = P8[(size_t)i0 * 16 + cg];
      PK_ROW(u0)
    }
    if (base < cnt) {  // 1-3 tail edges
      int j = min(base + eg, cnt - 1);
      int i0 = __shfl(idx, j);
      if (base + eg < cnt) {
        H8 u0;
        u0.v = P8[(size_t)i0 * 16 + cg];
        PK_ROW(u0)
      }
    }
  }
#pragma unroll
  for (int k = 0; k < 4; ++k) {
    acc[2 * k]     = (float)acch[k].x;
    acc[2 * k + 1] = (float)acch[k].y;
  }
#pragma unroll
  for (int j = 0; j < 8; ++j) {
    acc[j] += __shfl_xor(acc[j], 16);
    acc[j] += __shfl_xor(acc[j], 32);
  }
}

// gather 1: h1' = norm_src * relu(agg*nd + b), fp16 out
__global__ __launch_bounds__(256) void k_gather1(const half8* __restrict__ P8,
                                                 const int* __restrict__ row_end,
                                                 const int* __restrict__ csr,
                                                 const float* __restrict__ bias,
                                                 const float* __restrict__ norm_src,
                                                 half2v* __restrict__ outH, int N) {
  int wid = (blockIdx.x * 256 + threadIdx.x) >> 6;
  if (wid >= N) return;
  int lane = threadIdx.x & 63;
  int cg = lane & 15, eg = lane >> 4;
  int end = row_end[wid];
  int start = (wid == 0) ? 0 : row_end[wid - 1];
  float acc[8];
  gather_core(P8, csr, start, end, cg, eg, lane, acc);
  float nd = rsqrtf(fmaxf((float)(end - start), 1.0f));
  float ns = norm_src[wid];
  float2 b = ((const float2*)bias)[cg * 4 + eg];
  half2v o = {(_Float16)(fmaxf(acc[eg * 2] * nd + b.x, 0.f) * ns),
              (_Float16)(fmaxf(acc[eg * 2 + 1] * nd + b.y, 0.f) * ns)};
  outH[(size_t)wid * 64 + cg * 4 + eg] = o;
}

// gather 2: h2 = relu(agg*nd + b), fp32 out
__global__ __launch_bounds__(256) void k_gather2(const half8* __restrict__ P8,
                                                 const int* __restrict__ row_end,
                                                 const int* __restrict__ csr,
                                                 const float* __restrict__ bias,
                                                 float2* __restrict__ outH, int N) {
  int wid = (blockIdx.x * 256 + threadIdx.x) >> 6;
  if (wid >= N) return;
  int lane = threadIdx.x & 63;
  int cg = lane & 15, eg = lane >> 4;
  int end = row_end[wid];
  int start = (wid == 0) ? 0 : row_end[wid - 1];
  float acc[8];
  gather_core(P8, csr, start, end, cg, eg, lane, acc);
  float nd = rsqrtf(fmaxf((float)(end - start), 1.0f));
  float2 b = ((const float2*)bias)[cg * 4 + eg];
  float2 o;
  o.x = fmaxf(acc[eg * 2] * nd + b.x, 0.f);
  o.y = fmaxf(acc[eg * 2 + 1] * nd + b.y, 0.f);
  outH[(size_t)wid * 64 + cg * 4 + eg] = o;
}

// ---------------- segment-sum pooling over sorted graph_id ----------------
__global__ __launch_bounds__(256) void k_pool(const float* __restrict__ H,
                                              const int* __restrict__ gptr,
                                              float* __restrict__ pool) {
  int g = blockIdx.x >> 3, chunk = blockIdx.x & 7;
  int col = threadIdx.x & 127, rpar = threadIdx.x >> 7;
  int s = gptr[g], e = gptr[g + 1];
  float acc = 0.0f;
  for (int r = s + chunk * 2 + rpar; r < e; r += 16)
    acc += H[(size_t)r * D + col];
  __shared__ float red[256];
  red[threadIdx.x] = acc;
  __syncthreads();
  if (rpar == 0) atomicAdd(&pool[g * D + col], acc + red[threadIdx.x + 128]);
}

// ---------------- readout MLP ----------------
__global__ __launch_bounds__(128) void k_readout(const float* __restrict__ pool,
                                                 const int* __restrict__ gptr,
                                                 const float* __restrict__ Wr1,
                                                 const float* __restrict__ br1,
                                                 const float* __restrict__ Wr2,
                                                 const float* __restrict__ br2,
                                                 float* __restrict__ out) {
  int g = blockIdx.x;
  int j = threadIdx.x;
  __shared__ float hg[D];
  __shared__ float t1[D];
  float cnt = fmaxf((float)(gptr[g + 1] - gptr[g]), 1.0f);
  hg[j] = pool[(size_t)g * D + j] / cnt;
  __syncthreads();
  float a = br1[j];
  for (int k = 0; k < D; ++k) a += hg[k] * Wr1[(size_t)k * D + j];
  t1[j] = fmaxf(a, 0.0f);
  __syncthreads();
  float b = br2[j];
  for (int k = 0; k < D; ++k) b += t1[k] * Wr2[(size_t)k * D + j];
  out[(size_t)g * D + j] = b;
}

extern "C" void kernel_launch(void* const* d_in, const int* in_sizes, int n_in,
                              void* d_out, int out_size, void* d_ws, size_t ws_size,
                              hipStream_t stream) {
  const float* x   = (const float*)d_in[0];
  const int* edge  = (const int*)d_in[1];
  const int* gid   = (const int*)d_in[2];
  const float* W1  = (const float*)d_in[4];
  const float* b1  = (const float*)d_in[5];
  const float* W2  = (const float*)d_in[6];
  const float* b2  = (const float*)d_in[7];
  const float* Wr1 = (const float*)d_in[8];
  const float* br1 = (const float*)d_in[9];
  const float* Wr2 = (const float*)d_in[10];
  const float* br2 = (const float*)d_in[11];

  const int N = in_sizes[0] / D;   // 100000
  const int E = in_sizes[1] / 2;   // 1600000
  const int* src = edge;
  const int* dst = edge + E;
  const int nbkt = (N + BSZ - 1) >> BSH;  // 196

  // workspace layout
  float* bufA     = (float*)d_ws;                    // P (half N*128) lives here
  float* bufB     = bufA + (size_t)N * D;            // h1' (half N*128) lives here
  int* row_end    = (int*)(bufB + (size_t)N * D);    // N
  int* csr        = row_end + N;                     // E
  float* norm_src = (float*)(csr + E);               // N
  float* pool     = norm_src + N;                    // 64*128
  int* gptr       = (int*)(pool + 64 * D);           // 65
  int* cnt_d      = gptr + 65;                       // 256
  int* cnt_s      = cnt_d + 256;                     // 256 (adjacent to cnt_d)
  int* ptr_d      = cnt_s + 256;                     // 257
  int* ptr_s      = ptr_d + 257;                     // 257
  _Float16* Wt1   = (_Float16*)(ptr_s + 257);        // 128*128 halves
  _Float16* Wt2   = Wt1 + 128 * 128;                 // 128*128 halves
  // temporaries aliasing bufA (all consumed before gemm1 writes P)
  int* packed_d   = (int*)bufA;                      // E
  int* packed_s   = packed_d + E;                    // E
  int* blkbase_d  = packed_s + E;                    // NBLK*256
  int* blkbase_s  = blkbase_d + NBLK * 256;          // NBLK*256
  size_t need = ((size_t)2 * N * D + 2 * N + E + 64 * D + 65 + 1026 + 8192)
                * sizeof(float);
  if (ws_size < need) return;

  float* out_g = (float*)d_out;      // 64*128
  float* h_out = out_g + 64 * D;     // N*128

  _Float16* P   = (_Float16*)bufA;
  _Float16* h1p = (_Float16*)bufB;

  // prep: Wt transpose + zero cnt_d/cnt_s/pool (block 128)
  k_prep<<<129, 256, 0, stream>>>(W1, W2, Wt1, Wt2, cnt_d, pool);

  // graph structure via two-level counting sort
  k_coarse<<<NBLK, 512, 0, stream>>>(src, dst, cnt_d, cnt_s, blkbase_d, blkbase_s, E, nbkt);
  k_cscan<<<1, 256, 0, stream>>>(cnt_d, cnt_s, ptr_d, ptr_s, gid, gptr, nbkt, E, N);
  k_cscatter<<<NBLK, 512, 0, stream>>>(src, dst, ptr_d, ptr_s, blkbase_d, blkbase_s,
                                       packed_d, packed_s, E, nbkt);
  k_fine<<<2 * nbkt, 512, 0, stream>>>(packed_d, ptr_d, row_end, csr,
                                       packed_s, ptr_s, norm_src, N, nbkt);

  const int gemm_grid = (N + 63) / 64;

  // layer 1
  k_gemm1<<<gemm_grid, 256, 0, stream>>>(x, Wt1, norm_src, P, N);
  k_gather1<<<(N * 64 + 255) / 256, 256, 0, stream>>>(
      (const half8*)P, row_end, csr, b1, norm_src, (half2v*)h1p, N);

  // layer 2
  k_gemm2<<<gemm_grid, 256, 0, stream>>>(h1p, Wt2, P, N);
  k_gather2<<<(N * 64 + 255) / 256, 256, 0, stream>>>(
      (const half8*)P, row_end, csr, b2, (float2*)h_out, N);

  // pooling + readout
  k_pool<<<64 * 8, 256, 0, stream>>>(h_out, gptr, pool);
  k_readout<<<64, 128, 0, stream>>>(pool, gptr, Wr1, br1, Wr2, br2, out_g);
}